// Round 22
// baseline (997.340 us; speedup 1.0000x reference)
//
#include <hip/hip_runtime.h>
#include <hip/hip_bf16.h>
#include <math.h>

// Problem constants (SentenceLSTM)
static constexpr int BB = 256;    // batch
static constexpr int NR = 196;    // regions
static constexpr int DV = 1024;   // vis embed dim
static constexpr int HH = 1024;   // hidden
static constexpr int AT = 256;    // att dim
static constexpr int SI = 1024;   // sem input dim (ctx)
static constexpr int WI = 1024;   // topic width
static constexpr int IS = 256;    // stop inner dim
static constexpr int ST = 10;     // sentence steps

__device__ __forceinline__ float sigmoidf_(float x) { return 1.0f / (1.0f + expf(-x)); }

// bf16 round-to-nearest-even, bit-level
__device__ __forceinline__ ushort f2bf(float x) {
    uint u = __float_as_uint(x);
    return (ushort)((u + 0x7FFFu + ((u >> 16) & 1u)) >> 16);
}
__device__ __forceinline__ float bf2f(ushort b) { return __uint_as_float(((uint)b) << 16); }

using bf16x8 = __attribute__((ext_vector_type(8))) short;
using f32x4  = __attribute__((ext_vector_type(4))) float;
#define MFMA_B16(a, b, c) __builtin_amdgcn_mfma_f32_16x16x32_bf16((a), (b), (c), 0, 0, 0)

// ---------------------------------------------------------------------------
// Weight fp32 -> (hi,lo) bf16 split conversion. LIVE segments:
// 0:enc 1:W_hh(row-interleaved: r' = (r&1023)*4 + (r>>10)) 2:th 3:sp 4:sc
// 5:dec_att (hi only — lo is never consumed) 6:W_ih(plain) 7:topic_ctx(plain).
// ---------------------------------------------------------------------------
struct CvtTab { const float* s[8]; ushort* h[8]; ushort* l[8]; };

__global__ __launch_bounds__(256) void convert_split(CvtTab tab) {
    const int cum[9] = {0, 256, 4352, 5376, 5632, 5888, 6144, 10240, 11264};
    const int bid = blockIdx.x;
    int seg = 0;
#pragma unroll
    for (int i = 1; i < 8; ++i) if (bid >= cum[i]) seg = i;
    const float* s = tab.s[seg];
    ushort* h = tab.h[seg];
    ushort* l = tab.l[seg];
    const int r = bid - cum[seg];
    int rd = r;
    if (seg == 1) rd = (r & 1023) * 4 + (r >> 10);
    const int src = r * 1024 + threadIdx.x * 4;
    const size_t dst = (size_t)rd * 1024 + threadIdx.x * 4;
    float4 v = *(const float4*)(s + src);
    ushort h0 = f2bf(v.x), h1 = f2bf(v.y), h2 = f2bf(v.z), h3 = f2bf(v.w);
    uint2 hq;
    hq.x = h0 | ((uint)h1 << 16); hq.y = h2 | ((uint)h3 << 16);
    *(uint2*)(h + dst) = hq;
    if (seg != 5) {   // dec_att lo is dead — skip its math and store
        uint2 lq;
        ushort l0 = f2bf(v.x - bf2f(h0)), l1 = f2bf(v.y - bf2f(h1));
        ushort l2 = f2bf(v.z - bf2f(h2)), l3 = f2bf(v.w - bf2f(h3));
        lq.x = l0 | ((uint)l1 << 16); lq.y = l2 | ((uint)l3 << 16);
        *(uint2*)(l + dst) = lq;
    }
}

// ---------------------------------------------------------------------------
// convert_vis: vh = bf16(vis). 8 elems/thread, pure streaming.
// ---------------------------------------------------------------------------
__global__ __launch_bounds__(256) void convert_vis(
    const float* __restrict__ src, ushort* __restrict__ dst)
{
    const size_t i = ((size_t)blockIdx.x * 256 + threadIdx.x) * 8;
    const float4 v0 = *(const float4*)(src + i);
    const float4 v1 = *(const float4*)(src + i + 4);
    uint4 o;
    o.x = f2bf(v0.x) | ((uint)f2bf(v0.y) << 16);
    o.y = f2bf(v0.z) | ((uint)f2bf(v0.w) << 16);
    o.z = f2bf(v1.x) | ((uint)f2bf(v1.y) << 16);
    o.w = f2bf(v1.z) | ((uint)f2bf(v1.w) << 16);
    *(uint4*)(dst + i) = o;
}

// ---------------------------------------------------------------------------
// transpose_split: dh/dl = split(src^T) for src [1024,1024] fp32.
// ---------------------------------------------------------------------------
__global__ __launch_bounds__(256) void transpose_split(
    const float* __restrict__ src, ushort* __restrict__ dh, ushort* __restrict__ dl)
{
    __shared__ float T[32][33];
    const int tx = threadIdx.x & 31, ty = threadIdx.x >> 5;
    const int k0 = blockIdx.x * 32, n0 = blockIdx.y * 32;
#pragma unroll
    for (int j = 0; j < 4; ++j)
        T[ty + 8 * j][tx] = src[(size_t)(k0 + ty + 8 * j) * 1024 + n0 + tx];
    __syncthreads();
#pragma unroll
    for (int j = 0; j < 4; ++j) {
        const float v = T[tx][ty + 8 * j];
        const ushort h = f2bf(v);
        const size_t o = (size_t)(n0 + ty + 8 * j) * 1024 + k0 + tx;
        dh[o] = h;
        dl[o] = f2bf(v - bf2f(h));
    }
}

// ---------------------------------------------------------------------------
// foldbias2: merged bias folding for both heads.
// blocks 0..1023: bf_ih[n] = dot(W_ih[n], ctx_b) + b_ih[n]
// blocks 1024..1279: bf_tc[n] = dot(topic_ctx_w[n], ctx_b) + topic_ctx_b[n]
// ---------------------------------------------------------------------------
__global__ __launch_bounds__(256) void foldbias2(
    const float* __restrict__ Wih, const float* __restrict__ Wtc,
    const float* __restrict__ v,
    const float* __restrict__ bih, const float* __restrict__ btc,
    float* __restrict__ out_ih, float* __restrict__ out_tc)
{
    const int bid = blockIdx.x;
    const int lane = threadIdx.x & 63;
    const float* W; const float* b; float* out; int n;
    if (bid < 1024) { W = Wih; b = bih; out = out_ih; n = bid * 4 + (threadIdx.x >> 6); }
    else { W = Wtc; b = btc; out = out_tc; n = (bid - 1024) * 4 + (threadIdx.x >> 6); }
    const float* wr = W + (size_t)n * 1024;
    float p = 0.f;
#pragma unroll
    for (int i = 0; i < 4; ++i) {
        const float4 wv = *(const float4*)&wr[i * 256 + lane * 4];
        const float4 vv = *(const float4*)&v[i * 256 + lane * 4];
        p = fmaf(wv.x, vv.x, p); p = fmaf(wv.y, vv.y, p);
        p = fmaf(wv.z, vv.z, p); p = fmaf(wv.w, vv.w, p);
    }
    for (int off = 32; off; off >>= 1) p += __shfl_down(p, off);
    if (lane == 0) out[n] = p + b[n];
}

// ---------------------------------------------------------------------------
// mgemm_wsp: weight synthesis with PRE-SPLIT A. Csplit = A @ Wsplit^T.
// A hi/lo bf16 (from convert_split); W = ctx_w^T hi/lo. ILV: row interleave.
// ---------------------------------------------------------------------------
template <int ILV>
__global__ __launch_bounds__(256) void mgemm_wsp(
    const ushort* __restrict__ Ahg, const ushort* __restrict__ Alg,
    const ushort* __restrict__ Wh, const ushort* __restrict__ Wl,
    ushort* __restrict__ Ch, ushort* __restrict__ Cl, int N, int K)
{
    __shared__ __align__(16) ushort SM[4 * 64 * 40];
    ushort* Ah = SM; ushort* Al = SM + 2560; ushort* Bh = SM + 5120; ushort* Bl = SM + 7680;

    const int t = threadIdx.x;
    const int m0 = blockIdx.y * 64, n0 = blockIdx.x * 64;
    const int w = t >> 6, lane = t & 63;
    const int l15 = lane & 15, q = lane >> 4;
    const int sr = t >> 2, sq = (t & 3) * 8;
    const int nch = K >> 5;

    f32x4 acc[4] = {};
    uint4 pah, pal, pbh, pbl;
    auto pref = [&](int c) {
        const int k0 = c << 5;
        const size_t ab = (size_t)(m0 + sr) * K + k0 + sq;
        pah = *(const uint4*)&Ahg[ab];
        pal = *(const uint4*)&Alg[ab];
        pbh = *(const uint4*)&Wh[(size_t)(n0 + sr) * K + k0 + sq];
        pbl = *(const uint4*)&Wl[(size_t)(n0 + sr) * K + k0 + sq];
    };
    pref(0);

    for (int c = 0; c < nch; ++c) {
        __syncthreads();
        *(uint4*)&Ah[sr * 40 + sq] = pah;
        *(uint4*)&Al[sr * 40 + sq] = pal;
        *(uint4*)&Bh[sr * 40 + sq] = pbh;
        *(uint4*)&Bl[sr * 40 + sq] = pbl;
        __syncthreads();
        if (c + 1 < nch) pref(c + 1);
        const bf16x8 bh = *(const bf16x8*)&Bh[(w * 16 + l15) * 40 + q * 8];
        const bf16x8 bl = *(const bf16x8*)&Bl[(w * 16 + l15) * 40 + q * 8];
#pragma unroll
        for (int mi = 0; mi < 4; ++mi) {
            const bf16x8 ah = *(const bf16x8*)&Ah[(mi * 16 + l15) * 40 + q * 8];
            const bf16x8 al = *(const bf16x8*)&Al[(mi * 16 + l15) * 40 + q * 8];
            acc[mi] = MFMA_B16(ah, bh, acc[mi]);
            acc[mi] = MFMA_B16(ah, bl, acc[mi]);
            acc[mi] = MFMA_B16(al, bh, acc[mi]);
        }
    }

    const int col = n0 + w * 16 + l15;
#pragma unroll
    for (int mi = 0; mi < 4; ++mi) {
#pragma unroll
        for (int j = 0; j < 4; ++j) {
            const int row = m0 + mi * 16 + q * 4 + j;
            const int ro = ILV ? ((row & 1023) * 4 + (row >> 10)) : row;
            const float v = acc[mi][j];
            const ushort h = f2bf(v);
            Ch[(size_t)ro * N + col] = h;
            Cl[(size_t)ro * N + col] = f2bf(v - bf2f(h));
        }
    }
}

// ---------------------------------------------------------------------------
// mgemm_ps: deferred heads GEMM with PRE-SPLIT A (hi/lo bf16) for both
// passes: C = tanh( A1*W1^T + b1 + A2*W2^T + b2 ). 256 thr, 64x64 tile.
// OMAP=1: row=(s*BB+b) -> C[(b*ST+s)*ldc+col].
// ---------------------------------------------------------------------------
template <int OMAP>
__global__ __launch_bounds__(256) void mgemm_ps(
    const ushort* __restrict__ A1h, const ushort* __restrict__ A1l,
    const ushort* __restrict__ W1h, const ushort* __restrict__ W1l,
    const float* __restrict__ b1,
    const ushort* __restrict__ A2h, const ushort* __restrict__ A2l,
    const ushort* __restrict__ W2h, const ushort* __restrict__ W2l,
    const float* __restrict__ b2,
    float* __restrict__ C, int N, int K, int ldc)
{
    __shared__ __align__(16) ushort SM[4 * 64 * 40];
    ushort* Ah = SM; ushort* Al = SM + 2560; ushort* Bh = SM + 5120; ushort* Bl = SM + 7680;

    const int t = threadIdx.x;
    const int m0 = blockIdx.y * 64, n0 = blockIdx.x * 64;
    const int w = t >> 6, lane = t & 63;
    const int l15 = lane & 15, q = lane >> 4;
    const int sr = t >> 2, sq = (t & 3) * 8;
    const int KC = K >> 5, nch = 2 * KC;

    f32x4 acc[4] = {};
    uint4 pah, pal, pbh, pbl;

    auto pref = [&](int c) {
        const int pass = (c >= KC) ? 1 : 0;
        const int k0 = (c - pass * KC) << 5;
        const ushort* Axh = pass ? A2h : A1h;
        const ushort* Axl = pass ? A2l : A1l;
        const ushort* Wh = pass ? W2h : W1h;
        const ushort* Wl = pass ? W2l : W1l;
        const size_t ab = (size_t)(m0 + sr) * K + k0 + sq;
        pah = *(const uint4*)&Axh[ab];
        pal = *(const uint4*)&Axl[ab];
        pbh = *(const uint4*)&Wh[(size_t)(n0 + sr) * K + k0 + sq];
        pbl = *(const uint4*)&Wl[(size_t)(n0 + sr) * K + k0 + sq];
    };
    pref(0);

    for (int c = 0; c < nch; ++c) {
        __syncthreads();
        *(uint4*)&Ah[sr * 40 + sq] = pah;
        *(uint4*)&Al[sr * 40 + sq] = pal;
        *(uint4*)&Bh[sr * 40 + sq] = pbh;
        *(uint4*)&Bl[sr * 40 + sq] = pbl;
        __syncthreads();
        if (c + 1 < nch) pref(c + 1);
        const bf16x8 bh = *(const bf16x8*)&Bh[(w * 16 + l15) * 40 + q * 8];
        const bf16x8 bl = *(const bf16x8*)&Bl[(w * 16 + l15) * 40 + q * 8];
#pragma unroll
        for (int mi = 0; mi < 4; ++mi) {
            const bf16x8 ah = *(const bf16x8*)&Ah[(mi * 16 + l15) * 40 + q * 8];
            const bf16x8 al = *(const bf16x8*)&Al[(mi * 16 + l15) * 40 + q * 8];
            acc[mi] = MFMA_B16(ah, bh, acc[mi]);
            acc[mi] = MFMA_B16(ah, bl, acc[mi]);
            acc[mi] = MFMA_B16(al, bh, acc[mi]);
        }
    }

    const int col = n0 + w * 16 + l15;
    const float bias = b1[col] + b2[col];
#pragma unroll
    for (int mi = 0; mi < 4; ++mi) {
#pragma unroll
        for (int j = 0; j < 4; ++j) {
            const int row = m0 + mi * 16 + q * 4 + j;
            const float v = tanhf(acc[mi][j] + bias);
            if (OMAP)
                C[((size_t)(row & 255) * ST + (row >> 8)) * ldc + col] = v;
            else
                C[(size_t)row * ldc + col] = v;
        }
    }
}

// ---------------------------------------------------------------------------
// mgemm8_lstm: BK=64 body, pre-split activations; B-staging stride 64 with
// XOR swizzle; comb/G aliased into group-1 staging. LDS 53248 B.
// h state kept ONLY as hi/lo bf16 (no fp32 h write).
// ---------------------------------------------------------------------------
__global__ __launch_bounds__(512, 6) void mgemm8_lstm(
    const ushort* __restrict__ A1h, const ushort* __restrict__ A1l,
    const ushort* __restrict__ W1h, const ushort* __restrict__ W1l,
    const float* __restrict__ b1,
    const ushort* __restrict__ A2h, const ushort* __restrict__ A2l,
    const ushort* __restrict__ W2h, const ushort* __restrict__ W2l,
    const float* __restrict__ b2,
    int K, float* __restrict__ cvec,
    ushort* __restrict__ hnh, ushort* __restrict__ hnl)
{
    __shared__ __align__(16) ushort SM[26624];   // 53248 B

    const int t = threadIdx.x;
    const int m0 = blockIdx.y * 64, n0 = blockIdx.x * 32;
    const int w = t >> 6, lane = t & 63;
    const int g = w >> 2, wg = w & 3;
    const int l15 = lane & 15, q = lane >> 4;
    const int tl = t & 255;
    const int sr = tl >> 2, sq4 = (tl & 3) * 16;
    const int br = tl >> 3, bq = (tl & 7) * 8;
    const int mh = wg >> 1;
    const int colL = (wg & 1) * 16 + l15;

    ushort* Ah = SM + g * 13312;
    ushort* Al = Ah + 4608;
    ushort* Bh = Al + 4608;
    ushort* Bl = Bh + 2048;

    const int nchg = K >> 6;
    const ushort* Ahg = g ? A2h : A1h;
    const ushort* Alg = g ? A2l : A1l;
    const ushort* Wh  = g ? W2h : W1h;
    const ushort* Wl  = g ? W2l : W1l;

    const int bwi = br * 64 + (bq ^ ((br & 7) << 3));

    f32x4 acc[2] = {};
    uint4 pah0, pah1, pal0, pal1, pbh, pbl;
    auto pref = [&](int c) {
        const int k0 = c << 6;
        const size_t ab = (size_t)(m0 + sr) * K + k0 + sq4;
        pah0 = *(const uint4*)&Ahg[ab];
        pah1 = *(const uint4*)&Ahg[ab + 8];
        pal0 = *(const uint4*)&Alg[ab];
        pal1 = *(const uint4*)&Alg[ab + 8];
        pbh = *(const uint4*)&Wh[(size_t)(n0 + br) * K + k0 + bq];
        pbl = *(const uint4*)&Wl[(size_t)(n0 + br) * K + k0 + bq];
    };
    pref(0);

    for (int c = 0; c < nchg; ++c) {
        __syncthreads();
        *(uint4*)&Ah[sr * 72 + sq4]     = pah0;
        *(uint4*)&Ah[sr * 72 + sq4 + 8] = pah1;
        *(uint4*)&Al[sr * 72 + sq4]     = pal0;
        *(uint4*)&Al[sr * 72 + sq4 + 8] = pal1;
        *(uint4*)&Bh[bwi] = pbh;
        *(uint4*)&Bl[bwi] = pbl;
        __syncthreads();
        if (c + 1 < nchg) pref(c + 1);
#pragma unroll
        for (int ks = 0; ks < 2; ++ks) {
            const int bro = colL * 64 + ((ks * 32 + q * 8) ^ ((colL & 7) << 3));
            const bf16x8 bh = *(const bf16x8*)&Bh[bro];
            const bf16x8 bl = *(const bf16x8*)&Bl[bro];
#pragma unroll
            for (int i = 0; i < 2; ++i) {
                const int mi = mh * 2 + i;
                const bf16x8 ah = *(const bf16x8*)&Ah[(mi * 16 + l15) * 72 + ks * 32 + q * 8];
                const bf16x8 al = *(const bf16x8*)&Al[(mi * 16 + l15) * 72 + ks * 32 + q * 8];
                acc[i] = MFMA_B16(ah, bh, acc[i]);
                acc[i] = MFMA_B16(ah, bl, acc[i]);
                acc[i] = MFMA_B16(al, bh, acc[i]);
            }
        }
    }

    // combine group-1 partials into group-0
    float* comb = (float*)(SM + 13312);
    __syncthreads();
    if (g == 1) {
#pragma unroll
        for (int i = 0; i < 2; ++i)
#pragma unroll
            for (int j = 0; j < 4; ++j) comb[tl * 9 + i * 4 + j] = acc[i][j];
    }
    __syncthreads();
    if (g == 0) {
#pragma unroll
        for (int i = 0; i < 2; ++i)
#pragma unroll
            for (int j = 0; j < 4; ++j) acc[i][j] += comb[tl * 9 + i * 4 + j];
    }

    // LSTM pointwise. Gate cols interleaved (col' = unit*4+gate).
    float* G = (float*)(SM + 17920);
    if (g == 0) {
        const int colG = n0 + colL;
        const int gate = colG & 3, unit = colG >> 2;
        const float bias = b1[gate * 1024 + unit] + b2[gate * 1024 + unit];
#pragma unroll
        for (int i = 0; i < 2; ++i) {
            const int mi = mh * 2 + i;
#pragma unroll
            for (int j = 0; j < 4; ++j)
                G[(mi * 16 + q * 4 + j) * 40 + colL] = acc[i][j] + bias;
        }
    }
    __syncthreads();
    {
        const int row = t >> 3, ul = t & 7;
        const float4 g4 = *(const float4*)&G[row * 40 + ul * 4];  // i,f,g,o
        const size_t ci = (size_t)(m0 + row) * HH + (n0 >> 2) + ul;
        const float cn = sigmoidf_(g4.y) * cvec[ci] + sigmoidf_(g4.x) * tanhf(g4.z);
        cvec[ci] = cn;
        const float hv = sigmoidf_(g4.w) * tanhf(cn);
        const ushort hhi = f2bf(hv);
        hnh[ci] = hhi;
        hnl[ci] = f2bf(hv - bf2f(hhi));
    }
}

// ---------------------------------------------------------------------------
// mgemm_preb: vis_att(bf16) = vh(bf16) @ enc^T + b, 2-term (A-hi only,
// B hi+lo). Tile 128M x 256N, 512 threads, BK=32, reg prefetch after barrier.
// ---------------------------------------------------------------------------
__global__ __launch_bounds__(512) void mgemm_preb(
    const ushort* __restrict__ vh, const ushort* __restrict__ Wh, const ushort* __restrict__ Wl,
    const float* __restrict__ bias, ushort* __restrict__ C)
{
    __shared__ __align__(16) ushort Avh[128 * 40];
    __shared__ __align__(16) ushort Bh[256 * 40];
    __shared__ __align__(16) ushort Bl[256 * 40];

    const int t = threadIdx.x;
    const int m0 = blockIdx.x * 128;
    const int w = t >> 6, lane = t & 63;
    const int rg = w >> 2, cg = w & 3;
    const int l15 = lane & 15, q = lane >> 4;
    const int ar = t >> 2, ac = (t & 3) * 8;
    const int brr = t >> 1, bc = (t & 1) * 16;
    const int K = DV;

    f32x4 acc[4][4] = {};
    uint4 pa, pbh0, pbh1, pbl0, pbl1;
    auto pref = [&](int c) {
        const int k0 = c << 5;
        pa   = *(const uint4*)&vh[(size_t)(m0 + ar) * K + k0 + ac];
        const size_t bb = (size_t)brr * K + k0 + bc;
        pbh0 = *(const uint4*)&Wh[bb];
        pbh1 = *(const uint4*)&Wh[bb + 8];
        pbl0 = *(const uint4*)&Wl[bb];
        pbl1 = *(const uint4*)&Wl[bb + 8];
    };
    pref(0);

    for (int c = 0; c < 32; ++c) {
        __syncthreads();
        *(uint4*)&Avh[ar * 40 + ac] = pa;
        *(uint4*)&Bh[brr * 40 + bc]     = pbh0;
        *(uint4*)&Bh[brr * 40 + bc + 8] = pbh1;
        *(uint4*)&Bl[brr * 40 + bc]     = pbl0;
        *(uint4*)&Bl[brr * 40 + bc + 8] = pbl1;
        __syncthreads();
        if (c + 1 < 32) pref(c + 1);

        bf16x8 ah[4];
#pragma unroll
        for (int mi = 0; mi < 4; ++mi)
            ah[mi] = *(const bf16x8*)&Avh[(rg * 64 + mi * 16 + l15) * 40 + q * 8];
#pragma unroll
        for (int ni = 0; ni < 4; ++ni) {
            const bf16x8 bh = *(const bf16x8*)&Bh[(cg * 64 + ni * 16 + l15) * 40 + q * 8];
            const bf16x8 bl = *(const bf16x8*)&Bl[(cg * 64 + ni * 16 + l15) * 40 + q * 8];
#pragma unroll
            for (int mi = 0; mi < 4; ++mi) {
                acc[mi][ni] = MFMA_B16(ah[mi], bh, acc[mi][ni]);
                acc[mi][ni] = MFMA_B16(ah[mi], bl, acc[mi][ni]);
            }
        }
    }

#pragma unroll
    for (int ni = 0; ni < 4; ++ni) {
        const int col = cg * 64 + ni * 16 + l15;
        const float bb = bias[col];
#pragma unroll
        for (int mi = 0; mi < 4; ++mi)
#pragma unroll
            for (int j = 0; j < 4; ++j) {
                const int row = m0 + rg * 64 + mi * 16 + q * 4 + j;
                C[(size_t)row * AT + col] = f2bf(acc[mi][ni][j] + bb);
            }
    }
}

// ---------------------------------------------------------------------------
// att_step: per batch row b (one 1024-thread block): dec(bf16 weights,
// h reconstructed from hi/lo) + logits + softmax + apply. Emits hi/lo att.
// ---------------------------------------------------------------------------
template <int VBF>
__global__ __launch_bounds__(1024) void att_step(
    const ushort* __restrict__ vis_att,
    const ushort* __restrict__ hch, const ushort* __restrict__ hcl,
    const ushort* __restrict__ dec_wh, const float* __restrict__ dec_b,
    const float* __restrict__ fw, const float* __restrict__ fbp,
    const void* __restrict__ visp,
    ushort* __restrict__ att_h, ushort* __restrict__ att_l)
{
    const int b = blockIdx.x;
    const int t = threadIdx.x;
    const int lane = t & 63;
    const int w = t >> 6;

    __shared__ float hs[HH];
    __shared__ float decs[AT];
    __shared__ float fwv[AT];
    __shared__ float logit[NR + 4];
    __shared__ float sc[NR + 4];
    __shared__ float red[8];
    __shared__ float part[8][DV];

    hs[t] = bf2f(hch[(size_t)b * HH + t]) + bf2f(hcl[(size_t)b * HH + t]);
    if (t < AT) fwv[t] = fw[t];
    __syncthreads();
    const float fb = fbp[0];

    // phase 0: dec — bf16(hi) weights, 16B loads. Wave w owns a = w*16..+15.
#pragma unroll
    for (int j = 0; j < 16; ++j) {
        const int a = w * 16 + j;
        const ushort* wr = dec_wh + (size_t)a * HH;
        float p = 0.f;
#pragma unroll
        for (int i = 0; i < 2; ++i) {
            const uint4 wv = *(const uint4*)&wr[i * 512 + lane * 8];
            const float4 hv0 = *(const float4*)&hs[i * 512 + lane * 8];
            const float4 hv1 = *(const float4*)&hs[i * 512 + lane * 8 + 4];
            p = fmaf(bf2f((ushort)(wv.x & 0xFFFF)), hv0.x, p);
            p = fmaf(bf2f((ushort)(wv.x >> 16)),    hv0.y, p);
            p = fmaf(bf2f((ushort)(wv.y & 0xFFFF)), hv0.z, p);
            p = fmaf(bf2f((ushort)(wv.y >> 16)),    hv0.w, p);
            p = fmaf(bf2f((ushort)(wv.z & 0xFFFF)), hv1.x, p);
            p = fmaf(bf2f((ushort)(wv.z >> 16)),    hv1.y, p);
            p = fmaf(bf2f((ushort)(wv.w & 0xFFFF)), hv1.z, p);
            p = fmaf(bf2f((ushort)(wv.w >> 16)),    hv1.w, p);
        }
        for (int off = 32; off; off >>= 1) p += __shfl_down(p, off);
        if (lane == 0) decs[a] = p + dec_b[a];
    }
    __syncthreads();

    // phase 1: logits
    for (int n = w; n < NR; n += 16) {
        const ushort4 v4 = *(const ushort4*)&vis_att[((size_t)b * NR + n) * AT + lane * 4];
        const int a = lane * 4;
        float s = tanhf(bf2f(v4.x) + decs[a]) * fwv[a];
        s = fmaf(tanhf(bf2f(v4.y) + decs[a + 1]), fwv[a + 1], s);
        s = fmaf(tanhf(bf2f(v4.z) + decs[a + 2]), fwv[a + 2], s);
        s = fmaf(tanhf(bf2f(v4.w) + decs[a + 3]), fwv[a + 3], s);
        for (int off = 32; off; off >>= 1) s += __shfl_down(s, off);
        if (lane == 0) logit[n] = s + fb;
    }
    __syncthreads();

    // phase 2: softmax
    float m = -1e30f, e = 0.f;
    if (t < NR) m = logit[t];
    if (t < 256) {
        for (int off = 32; off; off >>= 1) m = fmaxf(m, __shfl_down(m, off));
        if (lane == 0) red[w] = m;
    }
    __syncthreads();
    m = fmaxf(fmaxf(red[0], red[1]), fmaxf(red[2], red[3]));
    if (t < NR) e = expf(logit[t] - m);
    if (t < 256) {
        float ss = e;
        for (int off = 32; off; off >>= 1) ss += __shfl_down(ss, off);
        if (lane == 0) red[4 + w] = ss;
    }
    __syncthreads();
    const float S = red[4] + red[5] + red[6] + red[7];
    if (t < NR) sc[t] = e / S;
    __syncthreads();

    // phase 3: apply — 8-way region split (25,25,25,25,24,24,24,24)
    const int slice = t >> 7;
    const int c8 = (t & 127) * 8;
    const int nbeg = (slice <= 4) ? 25 * slice : 100 + 24 * (slice - 4);
    const int nend = (slice < 4) ? nbeg + 25 : nbeg + 24;
    float a0 = 0.f, a1 = 0.f, a2 = 0.f, a3 = 0.f;
    float a4 = 0.f, a5 = 0.f, a6 = 0.f, a7 = 0.f;
    if (VBF) {
        const ushort* vb = (const ushort*)visp + (size_t)b * NR * DV + c8;
        for (int n = nbeg; n < nend; ++n) {
            const float s = sc[n];
            const uint4 v = *(const uint4*)&vb[(size_t)n * DV];
            a0 = fmaf(s, bf2f((ushort)(v.x & 0xFFFF)), a0);
            a1 = fmaf(s, bf2f((ushort)(v.x >> 16)), a1);
            a2 = fmaf(s, bf2f((ushort)(v.y & 0xFFFF)), a2);
            a3 = fmaf(s, bf2f((ushort)(v.y >> 16)), a3);
            a4 = fmaf(s, bf2f((ushort)(v.z & 0xFFFF)), a4);
            a5 = fmaf(s, bf2f((ushort)(v.z >> 16)), a5);
            a6 = fmaf(s, bf2f((ushort)(v.w & 0xFFFF)), a6);
            a7 = fmaf(s, bf2f((ushort)(v.w >> 16)), a7);
        }
    } else {
        const float* vb = (const float*)visp + (size_t)b * NR * DV + c8;
        for (int n = nbeg; n < nend; ++n) {
            const float s = sc[n];
            const float4 v0 = *(const float4*)&vb[(size_t)n * DV];
            const float4 v1 = *(const float4*)&vb[(size_t)n * DV + 4];
            a0 = fmaf(s, v0.x, a0); a1 = fmaf(s, v0.y, a1);
            a2 = fmaf(s, v0.z, a2); a3 = fmaf(s, v0.w, a3);
            a4 = fmaf(s, v1.x, a4); a5 = fmaf(s, v1.y, a5);
            a6 = fmaf(s, v1.z, a6); a7 = fmaf(s, v1.w, a7);
        }
    }
    float4 av0; av0.x = a0; av0.y = a1; av0.z = a2; av0.w = a3;
    float4 av1; av1.x = a4; av1.y = a5; av1.z = a6; av1.w = a7;
    *(float4*)&part[slice][c8]     = av0;
    *(float4*)&part[slice][c8 + 4] = av1;
    __syncthreads();
    const float v = ((part[0][t] + part[1][t]) + (part[2][t] + part[3][t]))
                  + ((part[4][t] + part[5][t]) + (part[6][t] + part[7][t]));
    const ushort vh16 = f2bf(v);
    att_h[(size_t)b * DV + t] = vh16;
    att_l[(size_t)b * DV + t] = f2bf(v - bf2f(vh16));
}

// ---------------------------------------------------------------------------
// batched final stop projection over all (s,b): row = s*BB + b.
// ---------------------------------------------------------------------------
__global__ __launch_bounds__(256) void stop_final_all(
    const float* __restrict__ pt, const float* __restrict__ fw,
    const float* __restrict__ fb, float* __restrict__ outp)
{
    const int row = blockIdx.x;
    const int s = row >> 8, b = row & 255;
    const int t = threadIdx.x;
    const int lane = t & 63;
    const int w = t >> 6;

    __shared__ float red[16];
    const float v = pt[(size_t)row * IS + t];
    float p0 = v * fw[t];
    float p1 = v * fw[IS + t];
    for (int off = 32; off; off >>= 1) {
        p0 += __shfl_down(p0, off);
        p1 += __shfl_down(p1, off);
    }
    if (lane == 0) { red[w] = p0; red[8 + w] = p1; }
    __syncthreads();
    if (t == 0) {
        outp[((size_t)b * ST + s) * 2 + 0] = red[0] + red[1] + red[2] + red[3] + fb[0];
        outp[((size_t)b * ST + s) * 2 + 1] = red[8] + red[9] + red[10] + red[11] + fb[1];
    }
}

// ---------------------------------------------------------------------------
extern "C" void kernel_launch(void* const* d_in, const int* in_sizes, int n_in,
                              void* d_out, int out_size, void* d_ws, size_t ws_size,
                              hipStream_t stream)
{
    const float* vis        = (const float*)d_in[0];
    const float* enc_att_w  = (const float*)d_in[2];
    const float* enc_att_b  = (const float*)d_in[3];
    const float* dec_att_w  = (const float*)d_in[4];
    const float* dec_att_b  = (const float*)d_in[5];
    const float* full_att_w = (const float*)d_in[6];
    const float* full_att_b = (const float*)d_in[7];
    const float* ctx_w      = (const float*)d_in[8];
    const float* ctx_b      = (const float*)d_in[9];
    const float* W_ih       = (const float*)d_in[10];
    const float* b_ih       = (const float*)d_in[11];
    const float* W_hh       = (const float*)d_in[12];
    const float* b_hh       = (const float*)d_in[13];
    const float* topic_hid_w = (const float*)d_in[14];
    const float* topic_hid_b = (const float*)d_in[15];
    const float* topic_ctx_w = (const float*)d_in[16];
    const float* topic_ctx_b = (const float*)d_in[17];
    const float* stop_prev_w = (const float*)d_in[18];
    const float* stop_prev_b = (const float*)d_in[19];
    const float* stop_cur_w  = (const float*)d_in[20];
    const float* stop_cur_b  = (const float*)d_in[21];
    const float* final_stop_w = (const float*)d_in[22];
    const float* final_stop_b = (const float*)d_in[23];

    float* out_topics = (float*)d_out;                        // [B, ST, WI]
    float* out_ps     = (float*)d_out + (size_t)BB * ST * WI; // [B, ST, 2]

    char* ws = (char*)d_ws;
    size_t off = 0;
    auto alloc = [&](size_t bytes) -> void* {
        void* p = (void*)(ws + off);
        off += (bytes + 255) & ~(size_t)255;
        return p;
    };
    ushort* vis_att = (ushort*)alloc((size_t)BB * NR * AT * 2);      // 25.7 MB
    // split pool: enc(256)+hh(4096)+th(1024)+sp(256)+sc(256)+dec(256)
    //             +W_ih(4096)+topic_ctx(1024) rows
    const size_t WTOT = (size_t)11264 * 1024;
    ushort* wh = (ushort*)alloc(WTOT * 2);                           // 23.1 MB
    ushort* wl = (ushort*)alloc(WTOT * 2);                           // 23.1 MB
    ushort* hh_h   = (ushort*)alloc((size_t)(ST + 1) * BB * HH * 2); // 5.8 MB
    ushort* hh_l   = (ushort*)alloc((size_t)(ST + 1) * BB * HH * 2); // 5.8 MB
    ushort* att_all_h = (ushort*)alloc((size_t)ST * BB * DV * 2);    // 5.25 MB
    ushort* att_all_l = (ushort*)alloc((size_t)ST * BB * DV * 2);    // 5.25 MB
    float* cbuf    = (float*)alloc((size_t)BB * HH * 4);
    float* pt_all  = (float*)alloc((size_t)ST * BB * IS * 4);        // 2.6 MB
    // ctx-fold pools
    ushort* ctT_h  = (ushort*)alloc((size_t)SI * DV * 2);            // 2 MB
    ushort* ctT_l  = (ushort*)alloc((size_t)SI * DV * 2);
    ushort* cmb_h  = (ushort*)alloc((size_t)4 * HH * SI * 2);        // 8.4 MB
    ushort* cmb_l  = (ushort*)alloc((size_t)4 * HH * SI * 2);
    ushort* tcc_h  = (ushort*)alloc((size_t)WI * SI * 2);            // 2 MB
    ushort* tcc_l  = (ushort*)alloc((size_t)WI * SI * 2);
    float* bf_ih   = (float*)alloc((size_t)4 * HH * 4);
    float* bf_tc   = (float*)alloc((size_t)WI * 4);
    if (off > ws_size) return;  // core workspace too small — fail visibly
    // bf16 copy of vis (98 MB); fallback to fp32-A path if no room
    ushort* vis_bf = nullptr;
    {
        const size_t need = (size_t)BB * NR * DV * 2;
        if (off + need <= ws_size) vis_bf = (ushort*)alloc(need);
    }

    // weight segment offsets (elements) within the pool
    const size_t O_ENC = 0;              // 256x1024
    const size_t O_HH  = 262144;         // 4096x1024 (row-interleaved)
    const size_t O_TH  = 4456448;        // 1024x1024
    const size_t O_SP  = 5505024;        // 256x1024
    const size_t O_SC  = 5767168;        // 256x1024
    const size_t O_DEC = 6029312;        // 256x1024 (hi used by att_step)
    const size_t O_IH2 = 6291456;        // 4096x1024 (plain, ws A)
    const size_t O_TC2 = 10485760;       // 1024x1024 (plain, ws A)

    CvtTab tab;
    const float* srcs[8] = {enc_att_w, W_hh, topic_hid_w, stop_prev_w, stop_cur_w,
                            dec_att_w, W_ih, topic_ctx_w};
    const size_t offs[8] = {O_ENC, O_HH, O_TH, O_SP, O_SC, O_DEC, O_IH2, O_TC2};
    for (int i = 0; i < 8; ++i) {
        tab.s[i] = srcs[i];
        tab.h[i] = wh + offs[i];
        tab.l[i] = wl + offs[i];
    }

    hipMemsetAsync(hh_h, 0, (size_t)BB * HH * 2, stream);    // h_0 hi = 0
    hipMemsetAsync(hh_l, 0, (size_t)BB * HH * 2, stream);    // h_0 lo = 0
    hipMemsetAsync(cbuf, 0, (size_t)BB * HH * 4, stream);    // c_0 = 0

    convert_split<<<11264, 256, 0, stream>>>(tab);

    // ---- ctx-fold precompute (pre-split A everywhere) ----
    transpose_split<<<dim3(SI / 32, DV / 32), 256, 0, stream>>>(ctx_w, ctT_h, ctT_l);
    mgemm_wsp<1><<<dim3(SI / 64, 4 * HH / 64), 256, 0, stream>>>(
        wh + O_IH2, wl + O_IH2, ctT_h, ctT_l, cmb_h, cmb_l, SI, DV);
    mgemm_wsp<0><<<dim3(SI / 64, WI / 64), 256, 0, stream>>>(
        wh + O_TC2, wl + O_TC2, ctT_h, ctT_l, tcc_h, tcc_l, SI, DV);
    foldbias2<<<1280, 256, 0, stream>>>(W_ih, topic_ctx_w, ctx_b,
                                        b_ih, topic_ctx_b, bf_ih, bf_tc);

    // hoisted encoder projection (split conversion + GEMM — measured best)
    convert_vis<<<(BB * NR * DV) / (256 * 8), 256, 0, stream>>>(vis, vis_bf);
    mgemm_preb<<<(BB * NR) / 128, 512, 0, stream>>>(
        vis_bf, wh + O_ENC, wl + O_ENC, enc_att_b, vis_att);

    for (int s = 0; s < ST; ++s) {
        ushort* hch = hh_h + (size_t)s * BB * HH;
        ushort* hcl = hh_l + (size_t)s * BB * HH;
        ushort* hnh = hh_h + (size_t)(s + 1) * BB * HH;
        ushort* hnl = hh_l + (size_t)(s + 1) * BB * HH;
        ushort* ath = att_all_h + (size_t)s * BB * DV;
        ushort* atl = att_all_l + (size_t)s * BB * DV;
        // fused dec(bf16 w, h from hi+lo) + logits + softmax + apply
        att_step<1><<<BB, 1024, 0, stream>>>(vis_att, hch, hcl, wh + O_DEC, dec_att_b,
                                             full_att_w, full_att_b, vis_bf,
                                             ath, atl);
        // gates = att @ W_comb^T + bf_ih + h @ W_hh^T + b_hh, fused LSTM
        mgemm8_lstm<<<dim3(4 * HH / 32, BB / 64), 512, 0, stream>>>(
            ath, atl, cmb_h, cmb_l, bf_ih,
            hch, hcl, wh + O_HH, wl + O_HH, b_hh,
            SI, cbuf, hnh, hnl);
    }

    // deferred batched heads over all steps (rows = s*BB + b), pre-split A
    mgemm_ps<1><<<dim3(WI / 64, (ST * BB) / 64), 256, 0, stream>>>(
        hh_h + (size_t)BB * HH, hh_l + (size_t)BB * HH,
        wh + O_TH, wl + O_TH, topic_hid_b,
        att_all_h, att_all_l, tcc_h, tcc_l, bf_tc,
        out_topics, WI, HH, WI);
    mgemm_ps<0><<<dim3(IS / 64, (ST * BB) / 64), 256, 0, stream>>>(
        hh_h, hh_l, wh + O_SP, wl + O_SP, stop_prev_b,
        hh_h + (size_t)BB * HH, hh_l + (size_t)BB * HH,
        wh + O_SC, wl + O_SC, stop_cur_b,
        pt_all, IS, HH, IS);
    stop_final_all<<<ST * BB, 256, 0, stream>>>(pt_all, final_stop_w, final_stop_b, out_ps);
}

// Round 23
// 961.943 us; speedup vs baseline: 1.0368x; 1.0368x over previous
//
#include <hip/hip_runtime.h>
#include <hip/hip_bf16.h>
#include <math.h>

// Problem constants (SentenceLSTM)
static constexpr int BB = 256;    // batch
static constexpr int NR = 196;    // regions
static constexpr int DV = 1024;   // vis embed dim
static constexpr int HH = 1024;   // hidden
static constexpr int AT = 256;    // att dim
static constexpr int SI = 1024;   // sem input dim (ctx)
static constexpr int WI = 1024;   // topic width
static constexpr int IS = 256;    // stop inner dim
static constexpr int ST = 10;     // sentence steps

__device__ __forceinline__ float sigmoidf_(float x) { return 1.0f / (1.0f + expf(-x)); }

// bf16 round-to-nearest-even, bit-level
__device__ __forceinline__ ushort f2bf(float x) {
    uint u = __float_as_uint(x);
    return (ushort)((u + 0x7FFFu + ((u >> 16) & 1u)) >> 16);
}
__device__ __forceinline__ float bf2f(ushort b) { return __uint_as_float(((uint)b) << 16); }

using bf16x8 = __attribute__((ext_vector_type(8))) short;
using f32x4  = __attribute__((ext_vector_type(4))) float;
#define MFMA_B16(a, b, c) __builtin_amdgcn_mfma_f32_16x16x32_bf16((a), (b), (c), 0, 0, 0)

// ---------------------------------------------------------------------------
// Weight fp32 -> (hi,lo) bf16 split conversion. LIVE segments:
// 0:enc 1:W_hh(row-interleaved: r' = (r&1023)*4 + (r>>10)) 2:th 3:sp 4:sc
// 5:dec_att (hi only — lo is never consumed) 6:W_ih(plain) 7:topic_ctx(plain).
// ---------------------------------------------------------------------------
struct CvtTab { const float* s[8]; ushort* h[8]; ushort* l[8]; };

__global__ __launch_bounds__(256) void convert_split(CvtTab tab) {
    const int cum[9] = {0, 256, 4352, 5376, 5632, 5888, 6144, 10240, 11264};
    const int bid = blockIdx.x;
    int seg = 0;
#pragma unroll
    for (int i = 1; i < 8; ++i) if (bid >= cum[i]) seg = i;
    const float* s = tab.s[seg];
    ushort* h = tab.h[seg];
    ushort* l = tab.l[seg];
    const int r = bid - cum[seg];
    int rd = r;
    if (seg == 1) rd = (r & 1023) * 4 + (r >> 10);
    const int src = r * 1024 + threadIdx.x * 4;
    const size_t dst = (size_t)rd * 1024 + threadIdx.x * 4;
    float4 v = *(const float4*)(s + src);
    ushort h0 = f2bf(v.x), h1 = f2bf(v.y), h2 = f2bf(v.z), h3 = f2bf(v.w);
    uint2 hq;
    hq.x = h0 | ((uint)h1 << 16); hq.y = h2 | ((uint)h3 << 16);
    *(uint2*)(h + dst) = hq;
    if (seg != 5) {   // dec_att lo is dead — skip its math and store
        uint2 lq;
        ushort l0 = f2bf(v.x - bf2f(h0)), l1 = f2bf(v.y - bf2f(h1));
        ushort l2 = f2bf(v.z - bf2f(h2)), l3 = f2bf(v.w - bf2f(h3));
        lq.x = l0 | ((uint)l1 << 16); lq.y = l2 | ((uint)l3 << 16);
        *(uint2*)(l + dst) = lq;
    }
}

// ---------------------------------------------------------------------------
// convert_vis: vh = bf16(vis). 8 elems/thread, pure streaming.
// ---------------------------------------------------------------------------
__global__ __launch_bounds__(256) void convert_vis(
    const float* __restrict__ src, ushort* __restrict__ dst)
{
    const size_t i = ((size_t)blockIdx.x * 256 + threadIdx.x) * 8;
    const float4 v0 = *(const float4*)(src + i);
    const float4 v1 = *(const float4*)(src + i + 4);
    uint4 o;
    o.x = f2bf(v0.x) | ((uint)f2bf(v0.y) << 16);
    o.y = f2bf(v0.z) | ((uint)f2bf(v0.w) << 16);
    o.z = f2bf(v1.x) | ((uint)f2bf(v1.y) << 16);
    o.w = f2bf(v1.z) | ((uint)f2bf(v1.w) << 16);
    *(uint4*)(dst + i) = o;
}

// ---------------------------------------------------------------------------
// transpose_split: dh/dl = split(src^T) for src [1024,1024] fp32.
// ---------------------------------------------------------------------------
__global__ __launch_bounds__(256) void transpose_split(
    const float* __restrict__ src, ushort* __restrict__ dh, ushort* __restrict__ dl)
{
    __shared__ float T[32][33];
    const int tx = threadIdx.x & 31, ty = threadIdx.x >> 5;
    const int k0 = blockIdx.x * 32, n0 = blockIdx.y * 32;
#pragma unroll
    for (int j = 0; j < 4; ++j)
        T[ty + 8 * j][tx] = src[(size_t)(k0 + ty + 8 * j) * 1024 + n0 + tx];
    __syncthreads();
#pragma unroll
    for (int j = 0; j < 4; ++j) {
        const float v = T[tx][ty + 8 * j];
        const ushort h = f2bf(v);
        const size_t o = (size_t)(n0 + ty + 8 * j) * 1024 + k0 + tx;
        dh[o] = h;
        dl[o] = f2bf(v - bf2f(h));
    }
}

// ---------------------------------------------------------------------------
// foldbias2: merged bias folding for both heads.
// blocks 0..1023: bf_ih[n] = dot(W_ih[n], ctx_b) + b_ih[n]
// blocks 1024..1279: bf_tc[n] = dot(topic_ctx_w[n], ctx_b) + topic_ctx_b[n]
// ---------------------------------------------------------------------------
__global__ __launch_bounds__(256) void foldbias2(
    const float* __restrict__ Wih, const float* __restrict__ Wtc,
    const float* __restrict__ v,
    const float* __restrict__ bih, const float* __restrict__ btc,
    float* __restrict__ out_ih, float* __restrict__ out_tc)
{
    const int bid = blockIdx.x;
    const int lane = threadIdx.x & 63;
    const float* W; const float* b; float* out; int n;
    if (bid < 1024) { W = Wih; b = bih; out = out_ih; n = bid * 4 + (threadIdx.x >> 6); }
    else { W = Wtc; b = btc; out = out_tc; n = (bid - 1024) * 4 + (threadIdx.x >> 6); }
    const float* wr = W + (size_t)n * 1024;
    float p = 0.f;
#pragma unroll
    for (int i = 0; i < 4; ++i) {
        const float4 wv = *(const float4*)&wr[i * 256 + lane * 4];
        const float4 vv = *(const float4*)&v[i * 256 + lane * 4];
        p = fmaf(wv.x, vv.x, p); p = fmaf(wv.y, vv.y, p);
        p = fmaf(wv.z, vv.z, p); p = fmaf(wv.w, vv.w, p);
    }
    for (int off = 32; off; off >>= 1) p += __shfl_down(p, off);
    if (lane == 0) out[n] = p + b[n];
}

// ---------------------------------------------------------------------------
// mgemm_wsp: weight synthesis with PRE-SPLIT A. Csplit = A @ Wsplit^T.
// A hi/lo bf16 (from convert_split); W = ctx_w^T hi/lo. ILV: row interleave.
// ---------------------------------------------------------------------------
template <int ILV>
__global__ __launch_bounds__(256) void mgemm_wsp(
    const ushort* __restrict__ Ahg, const ushort* __restrict__ Alg,
    const ushort* __restrict__ Wh, const ushort* __restrict__ Wl,
    ushort* __restrict__ Ch, ushort* __restrict__ Cl, int N, int K)
{
    __shared__ __align__(16) ushort SM[4 * 64 * 40];
    ushort* Ah = SM; ushort* Al = SM + 2560; ushort* Bh = SM + 5120; ushort* Bl = SM + 7680;

    const int t = threadIdx.x;
    const int m0 = blockIdx.y * 64, n0 = blockIdx.x * 64;
    const int w = t >> 6, lane = t & 63;
    const int l15 = lane & 15, q = lane >> 4;
    const int sr = t >> 2, sq = (t & 3) * 8;
    const int nch = K >> 5;

    f32x4 acc[4] = {};
    uint4 pah, pal, pbh, pbl;
    auto pref = [&](int c) {
        const int k0 = c << 5;
        const size_t ab = (size_t)(m0 + sr) * K + k0 + sq;
        pah = *(const uint4*)&Ahg[ab];
        pal = *(const uint4*)&Alg[ab];
        pbh = *(const uint4*)&Wh[(size_t)(n0 + sr) * K + k0 + sq];
        pbl = *(const uint4*)&Wl[(size_t)(n0 + sr) * K + k0 + sq];
    };
    pref(0);

    for (int c = 0; c < nch; ++c) {
        __syncthreads();
        *(uint4*)&Ah[sr * 40 + sq] = pah;
        *(uint4*)&Al[sr * 40 + sq] = pal;
        *(uint4*)&Bh[sr * 40 + sq] = pbh;
        *(uint4*)&Bl[sr * 40 + sq] = pbl;
        __syncthreads();
        if (c + 1 < nch) pref(c + 1);
        const bf16x8 bh = *(const bf16x8*)&Bh[(w * 16 + l15) * 40 + q * 8];
        const bf16x8 bl = *(const bf16x8*)&Bl[(w * 16 + l15) * 40 + q * 8];
#pragma unroll
        for (int mi = 0; mi < 4; ++mi) {
            const bf16x8 ah = *(const bf16x8*)&Ah[(mi * 16 + l15) * 40 + q * 8];
            const bf16x8 al = *(const bf16x8*)&Al[(mi * 16 + l15) * 40 + q * 8];
            acc[mi] = MFMA_B16(ah, bh, acc[mi]);
            acc[mi] = MFMA_B16(ah, bl, acc[mi]);
            acc[mi] = MFMA_B16(al, bh, acc[mi]);
        }
    }

    const int col = n0 + w * 16 + l15;
#pragma unroll
    for (int mi = 0; mi < 4; ++mi) {
#pragma unroll
        for (int j = 0; j < 4; ++j) {
            const int row = m0 + mi * 16 + q * 4 + j;
            const int ro = ILV ? ((row & 1023) * 4 + (row >> 10)) : row;
            const float v = acc[mi][j];
            const ushort h = f2bf(v);
            Ch[(size_t)ro * N + col] = h;
            Cl[(size_t)ro * N + col] = f2bf(v - bf2f(h));
        }
    }
}

// ---------------------------------------------------------------------------
// mgemm_heads: MERGED deferred-head GEMM. 800 blocks, 1D:
//   bid <  640: topic tile (bx=bid&15, by=bid>>4), OMAP row remap, ldc=WI
//   bid >= 640: stop  tile (bx=(bid-640)&3, by=(bid-640)>>2), ldc=IS
// Both: C = tanh(A1*W1^T + A2*W2^T + b1+b2), K=1024, pre-split operands.
// ---------------------------------------------------------------------------
__global__ __launch_bounds__(256) void mgemm_heads(
    const ushort* __restrict__ tA1h, const ushort* __restrict__ tA1l,
    const ushort* __restrict__ tW1h, const ushort* __restrict__ tW1l,
    const float* __restrict__ tb1,
    const ushort* __restrict__ tA2h, const ushort* __restrict__ tA2l,
    const ushort* __restrict__ tW2h, const ushort* __restrict__ tW2l,
    const float* __restrict__ tb2,
    float* __restrict__ tC,
    const ushort* __restrict__ sA1h, const ushort* __restrict__ sA1l,
    const ushort* __restrict__ sW1h, const ushort* __restrict__ sW1l,
    const float* __restrict__ sb1,
    const ushort* __restrict__ sA2h, const ushort* __restrict__ sA2l,
    const ushort* __restrict__ sW2h, const ushort* __restrict__ sW2l,
    const float* __restrict__ sb2,
    float* __restrict__ sC)
{
    __shared__ __align__(16) ushort SM[4 * 64 * 40];
    ushort* Ah = SM; ushort* Al = SM + 2560; ushort* Bh = SM + 5120; ushort* Bl = SM + 7680;

    const int bid = blockIdx.x;
    const int topic = (bid < 640) ? 1 : 0;
    const int lb = topic ? bid : (bid - 640);
    const int bx = topic ? (lb & 15) : (lb & 3);
    const int by = topic ? (lb >> 4) : (lb >> 2);
    const int m0 = by * 64, n0 = bx * 64;
    const int ldc = topic ? WI : IS;

    const ushort* A1h = topic ? tA1h : sA1h;  const ushort* A1l = topic ? tA1l : sA1l;
    const ushort* W1h = topic ? tW1h : sW1h;  const ushort* W1l = topic ? tW1l : sW1l;
    const float*  b1  = topic ? tb1  : sb1;
    const ushort* A2h = topic ? tA2h : sA2h;  const ushort* A2l = topic ? tA2l : sA2l;
    const ushort* W2h = topic ? tW2h : sW2h;  const ushort* W2l = topic ? tW2l : sW2l;
    const float*  b2  = topic ? tb2  : sb2;
    float* C = topic ? tC : sC;

    const int t = threadIdx.x;
    const int w = t >> 6, lane = t & 63;
    const int l15 = lane & 15, q = lane >> 4;
    const int sr = t >> 2, sq = (t & 3) * 8;
    const int K = HH;
    const int KC = K >> 5, nch = 2 * KC;

    f32x4 acc[4] = {};
    uint4 pah, pal, pbh, pbl;

    auto pref = [&](int c) {
        const int pass = (c >= KC) ? 1 : 0;
        const int k0 = (c - pass * KC) << 5;
        const ushort* Axh = pass ? A2h : A1h;
        const ushort* Axl = pass ? A2l : A1l;
        const ushort* Wh = pass ? W2h : W1h;
        const ushort* Wl = pass ? W2l : W1l;
        const size_t ab = (size_t)(m0 + sr) * K + k0 + sq;
        pah = *(const uint4*)&Axh[ab];
        pal = *(const uint4*)&Axl[ab];
        pbh = *(const uint4*)&Wh[(size_t)(n0 + sr) * K + k0 + sq];
        pbl = *(const uint4*)&Wl[(size_t)(n0 + sr) * K + k0 + sq];
    };
    pref(0);

    for (int c = 0; c < nch; ++c) {
        __syncthreads();
        *(uint4*)&Ah[sr * 40 + sq] = pah;
        *(uint4*)&Al[sr * 40 + sq] = pal;
        *(uint4*)&Bh[sr * 40 + sq] = pbh;
        *(uint4*)&Bl[sr * 40 + sq] = pbl;
        __syncthreads();
        if (c + 1 < nch) pref(c + 1);
        const bf16x8 bh = *(const bf16x8*)&Bh[(w * 16 + l15) * 40 + q * 8];
        const bf16x8 bl = *(const bf16x8*)&Bl[(w * 16 + l15) * 40 + q * 8];
#pragma unroll
        for (int mi = 0; mi < 4; ++mi) {
            const bf16x8 ah = *(const bf16x8*)&Ah[(mi * 16 + l15) * 40 + q * 8];
            const bf16x8 al = *(const bf16x8*)&Al[(mi * 16 + l15) * 40 + q * 8];
            acc[mi] = MFMA_B16(ah, bh, acc[mi]);
            acc[mi] = MFMA_B16(ah, bl, acc[mi]);
            acc[mi] = MFMA_B16(al, bh, acc[mi]);
        }
    }

    const int col = n0 + w * 16 + l15;
    const float bias = b1[col] + b2[col];
#pragma unroll
    for (int mi = 0; mi < 4; ++mi) {
#pragma unroll
        for (int j = 0; j < 4; ++j) {
            const int row = m0 + mi * 16 + q * 4 + j;
            const float v = tanhf(acc[mi][j] + bias);
            if (topic)
                C[((size_t)(row & 255) * ST + (row >> 8)) * ldc + col] = v;
            else
                C[(size_t)row * ldc + col] = v;
        }
    }
}

// ---------------------------------------------------------------------------
// mgemm8_lstm: BK=64 body, pre-split activations; B-staging stride 64 with
// XOR swizzle; comb/G aliased into group-1 staging. LDS 53248 B.
// h state kept ONLY as hi/lo bf16 (no fp32 h write).
// ---------------------------------------------------------------------------
__global__ __launch_bounds__(512, 6) void mgemm8_lstm(
    const ushort* __restrict__ A1h, const ushort* __restrict__ A1l,
    const ushort* __restrict__ W1h, const ushort* __restrict__ W1l,
    const float* __restrict__ b1,
    const ushort* __restrict__ A2h, const ushort* __restrict__ A2l,
    const ushort* __restrict__ W2h, const ushort* __restrict__ W2l,
    const float* __restrict__ b2,
    int K, float* __restrict__ cvec,
    ushort* __restrict__ hnh, ushort* __restrict__ hnl)
{
    __shared__ __align__(16) ushort SM[26624];   // 53248 B

    const int t = threadIdx.x;
    const int m0 = blockIdx.y * 64, n0 = blockIdx.x * 32;
    const int w = t >> 6, lane = t & 63;
    const int g = w >> 2, wg = w & 3;
    const int l15 = lane & 15, q = lane >> 4;
    const int tl = t & 255;
    const int sr = tl >> 2, sq4 = (tl & 3) * 16;
    const int br = tl >> 3, bq = (tl & 7) * 8;
    const int mh = wg >> 1;
    const int colL = (wg & 1) * 16 + l15;

    ushort* Ah = SM + g * 13312;
    ushort* Al = Ah + 4608;
    ushort* Bh = Al + 4608;
    ushort* Bl = Bh + 2048;

    const int nchg = K >> 6;
    const ushort* Ahg = g ? A2h : A1h;
    const ushort* Alg = g ? A2l : A1l;
    const ushort* Wh  = g ? W2h : W1h;
    const ushort* Wl  = g ? W2l : W1l;

    const int bwi = br * 64 + (bq ^ ((br & 7) << 3));

    f32x4 acc[2] = {};
    uint4 pah0, pah1, pal0, pal1, pbh, pbl;
    auto pref = [&](int c) {
        const int k0 = c << 6;
        const size_t ab = (size_t)(m0 + sr) * K + k0 + sq4;
        pah0 = *(const uint4*)&Ahg[ab];
        pah1 = *(const uint4*)&Ahg[ab + 8];
        pal0 = *(const uint4*)&Alg[ab];
        pal1 = *(const uint4*)&Alg[ab + 8];
        pbh = *(const uint4*)&Wh[(size_t)(n0 + br) * K + k0 + bq];
        pbl = *(const uint4*)&Wl[(size_t)(n0 + br) * K + k0 + bq];
    };
    pref(0);

    for (int c = 0; c < nchg; ++c) {
        __syncthreads();
        *(uint4*)&Ah[sr * 72 + sq4]     = pah0;
        *(uint4*)&Ah[sr * 72 + sq4 + 8] = pah1;
        *(uint4*)&Al[sr * 72 + sq4]     = pal0;
        *(uint4*)&Al[sr * 72 + sq4 + 8] = pal1;
        *(uint4*)&Bh[bwi] = pbh;
        *(uint4*)&Bl[bwi] = pbl;
        __syncthreads();
        if (c + 1 < nchg) pref(c + 1);
#pragma unroll
        for (int ks = 0; ks < 2; ++ks) {
            const int bro = colL * 64 + ((ks * 32 + q * 8) ^ ((colL & 7) << 3));
            const bf16x8 bh = *(const bf16x8*)&Bh[bro];
            const bf16x8 bl = *(const bf16x8*)&Bl[bro];
#pragma unroll
            for (int i = 0; i < 2; ++i) {
                const int mi = mh * 2 + i;
                const bf16x8 ah = *(const bf16x8*)&Ah[(mi * 16 + l15) * 72 + ks * 32 + q * 8];
                const bf16x8 al = *(const bf16x8*)&Al[(mi * 16 + l15) * 72 + ks * 32 + q * 8];
                acc[i] = MFMA_B16(ah, bh, acc[i]);
                acc[i] = MFMA_B16(ah, bl, acc[i]);
                acc[i] = MFMA_B16(al, bh, acc[i]);
            }
        }
    }

    // combine group-1 partials into group-0
    float* comb = (float*)(SM + 13312);
    __syncthreads();
    if (g == 1) {
#pragma unroll
        for (int i = 0; i < 2; ++i)
#pragma unroll
            for (int j = 0; j < 4; ++j) comb[tl * 9 + i * 4 + j] = acc[i][j];
    }
    __syncthreads();
    if (g == 0) {
#pragma unroll
        for (int i = 0; i < 2; ++i)
#pragma unroll
            for (int j = 0; j < 4; ++j) acc[i][j] += comb[tl * 9 + i * 4 + j];
    }

    // LSTM pointwise. Gate cols interleaved (col' = unit*4+gate).
    float* G = (float*)(SM + 17920);
    if (g == 0) {
        const int colG = n0 + colL;
        const int gate = colG & 3, unit = colG >> 2;
        const float bias = b1[gate * 1024 + unit] + b2[gate * 1024 + unit];
#pragma unroll
        for (int i = 0; i < 2; ++i) {
            const int mi = mh * 2 + i;
#pragma unroll
            for (int j = 0; j < 4; ++j)
                G[(mi * 16 + q * 4 + j) * 40 + colL] = acc[i][j] + bias;
        }
    }
    __syncthreads();
    {
        const int row = t >> 3, ul = t & 7;
        const float4 g4 = *(const float4*)&G[row * 40 + ul * 4];  // i,f,g,o
        const size_t ci = (size_t)(m0 + row) * HH + (n0 >> 2) + ul;
        const float cn = sigmoidf_(g4.y) * cvec[ci] + sigmoidf_(g4.x) * tanhf(g4.z);
        cvec[ci] = cn;
        const float hv = sigmoidf_(g4.w) * tanhf(cn);
        const ushort hhi = f2bf(hv);
        hnh[ci] = hhi;
        hnl[ci] = f2bf(hv - bf2f(hhi));
    }
}

// ---------------------------------------------------------------------------
// mgemm_preb: vis_att(bf16) = vh(bf16) @ enc^T + b, 2-term (A-hi only,
// B hi+lo). Tile 128M x 256N, 512 threads, BK=32, reg prefetch after barrier.
// ---------------------------------------------------------------------------
__global__ __launch_bounds__(512) void mgemm_preb(
    const ushort* __restrict__ vh, const ushort* __restrict__ Wh, const ushort* __restrict__ Wl,
    const float* __restrict__ bias, ushort* __restrict__ C)
{
    __shared__ __align__(16) ushort Avh[128 * 40];
    __shared__ __align__(16) ushort Bh[256 * 40];
    __shared__ __align__(16) ushort Bl[256 * 40];

    const int t = threadIdx.x;
    const int m0 = blockIdx.x * 128;
    const int w = t >> 6, lane = t & 63;
    const int rg = w >> 2, cg = w & 3;
    const int l15 = lane & 15, q = lane >> 4;
    const int ar = t >> 2, ac = (t & 3) * 8;
    const int brr = t >> 1, bc = (t & 1) * 16;
    const int K = DV;

    f32x4 acc[4][4] = {};
    uint4 pa, pbh0, pbh1, pbl0, pbl1;
    auto pref = [&](int c) {
        const int k0 = c << 5;
        pa   = *(const uint4*)&vh[(size_t)(m0 + ar) * K + k0 + ac];
        const size_t bb = (size_t)brr * K + k0 + bc;
        pbh0 = *(const uint4*)&Wh[bb];
        pbh1 = *(const uint4*)&Wh[bb + 8];
        pbl0 = *(const uint4*)&Wl[bb];
        pbl1 = *(const uint4*)&Wl[bb + 8];
    };
    pref(0);

    for (int c = 0; c < 32; ++c) {
        __syncthreads();
        *(uint4*)&Avh[ar * 40 + ac] = pa;
        *(uint4*)&Bh[brr * 40 + bc]     = pbh0;
        *(uint4*)&Bh[brr * 40 + bc + 8] = pbh1;
        *(uint4*)&Bl[brr * 40 + bc]     = pbl0;
        *(uint4*)&Bl[brr * 40 + bc + 8] = pbl1;
        __syncthreads();
        if (c + 1 < 32) pref(c + 1);

        bf16x8 ah[4];
#pragma unroll
        for (int mi = 0; mi < 4; ++mi)
            ah[mi] = *(const bf16x8*)&Avh[(rg * 64 + mi * 16 + l15) * 40 + q * 8];
#pragma unroll
        for (int ni = 0; ni < 4; ++ni) {
            const bf16x8 bh = *(const bf16x8*)&Bh[(cg * 64 + ni * 16 + l15) * 40 + q * 8];
            const bf16x8 bl = *(const bf16x8*)&Bl[(cg * 64 + ni * 16 + l15) * 40 + q * 8];
#pragma unroll
            for (int mi = 0; mi < 4; ++mi) {
                acc[mi][ni] = MFMA_B16(ah[mi], bh, acc[mi][ni]);
                acc[mi][ni] = MFMA_B16(ah[mi], bl, acc[mi][ni]);
            }
        }
    }

#pragma unroll
    for (int ni = 0; ni < 4; ++ni) {
        const int col = cg * 64 + ni * 16 + l15;
        const float bb = bias[col];
#pragma unroll
        for (int mi = 0; mi < 4; ++mi)
#pragma unroll
            for (int j = 0; j < 4; ++j) {
                const int row = m0 + rg * 64 + mi * 16 + q * 4 + j;
                C[(size_t)row * AT + col] = f2bf(acc[mi][ni][j] + bb);
            }
    }
}

// ---------------------------------------------------------------------------
// att_step: per batch row b (one 1024-thread block): dec(bf16 weights,
// h reconstructed from hi/lo) + logits + softmax + apply. Emits hi/lo att.
// ---------------------------------------------------------------------------
template <int VBF>
__global__ __launch_bounds__(1024) void att_step(
    const ushort* __restrict__ vis_att,
    const ushort* __restrict__ hch, const ushort* __restrict__ hcl,
    const ushort* __restrict__ dec_wh, const float* __restrict__ dec_b,
    const float* __restrict__ fw, const float* __restrict__ fbp,
    const void* __restrict__ visp,
    ushort* __restrict__ att_h, ushort* __restrict__ att_l)
{
    const int b = blockIdx.x;
    const int t = threadIdx.x;
    const int lane = t & 63;
    const int w = t >> 6;

    __shared__ float hs[HH];
    __shared__ float decs[AT];
    __shared__ float fwv[AT];
    __shared__ float logit[NR + 4];
    __shared__ float sc[NR + 4];
    __shared__ float red[8];
    __shared__ float part[8][DV];

    hs[t] = bf2f(hch[(size_t)b * HH + t]) + bf2f(hcl[(size_t)b * HH + t]);
    if (t < AT) fwv[t] = fw[t];
    __syncthreads();
    const float fb = fbp[0];

    // phase 0: dec — bf16(hi) weights, 16B loads. Wave w owns a = w*16..+15.
#pragma unroll
    for (int j = 0; j < 16; ++j) {
        const int a = w * 16 + j;
        const ushort* wr = dec_wh + (size_t)a * HH;
        float p = 0.f;
#pragma unroll
        for (int i = 0; i < 2; ++i) {
            const uint4 wv = *(const uint4*)&wr[i * 512 + lane * 8];
            const float4 hv0 = *(const float4*)&hs[i * 512 + lane * 8];
            const float4 hv1 = *(const float4*)&hs[i * 512 + lane * 8 + 4];
            p = fmaf(bf2f((ushort)(wv.x & 0xFFFF)), hv0.x, p);
            p = fmaf(bf2f((ushort)(wv.x >> 16)),    hv0.y, p);
            p = fmaf(bf2f((ushort)(wv.y & 0xFFFF)), hv0.z, p);
            p = fmaf(bf2f((ushort)(wv.y >> 16)),    hv0.w, p);
            p = fmaf(bf2f((ushort)(wv.z & 0xFFFF)), hv1.x, p);
            p = fmaf(bf2f((ushort)(wv.z >> 16)),    hv1.y, p);
            p = fmaf(bf2f((ushort)(wv.w & 0xFFFF)), hv1.z, p);
            p = fmaf(bf2f((ushort)(wv.w >> 16)),    hv1.w, p);
        }
        for (int off = 32; off; off >>= 1) p += __shfl_down(p, off);
        if (lane == 0) decs[a] = p + dec_b[a];
    }
    __syncthreads();

    // phase 1: logits
    for (int n = w; n < NR; n += 16) {
        const ushort4 v4 = *(const ushort4*)&vis_att[((size_t)b * NR + n) * AT + lane * 4];
        const int a = lane * 4;
        float s = tanhf(bf2f(v4.x) + decs[a]) * fwv[a];
        s = fmaf(tanhf(bf2f(v4.y) + decs[a + 1]), fwv[a + 1], s);
        s = fmaf(tanhf(bf2f(v4.z) + decs[a + 2]), fwv[a + 2], s);
        s = fmaf(tanhf(bf2f(v4.w) + decs[a + 3]), fwv[a + 3], s);
        for (int off = 32; off; off >>= 1) s += __shfl_down(s, off);
        if (lane == 0) logit[n] = s + fb;
    }
    __syncthreads();

    // phase 2: softmax
    float m = -1e30f, e = 0.f;
    if (t < NR) m = logit[t];
    if (t < 256) {
        for (int off = 32; off; off >>= 1) m = fmaxf(m, __shfl_down(m, off));
        if (lane == 0) red[w] = m;
    }
    __syncthreads();
    m = fmaxf(fmaxf(red[0], red[1]), fmaxf(red[2], red[3]));
    if (t < NR) e = expf(logit[t] - m);
    if (t < 256) {
        float ss = e;
        for (int off = 32; off; off >>= 1) ss += __shfl_down(ss, off);
        if (lane == 0) red[4 + w] = ss;
    }
    __syncthreads();
    const float S = red[4] + red[5] + red[6] + red[7];
    if (t < NR) sc[t] = e / S;
    __syncthreads();

    // phase 3: apply — 8-way region split (25,25,25,25,24,24,24,24)
    const int slice = t >> 7;
    const int c8 = (t & 127) * 8;
    const int nbeg = (slice <= 4) ? 25 * slice : 100 + 24 * (slice - 4);
    const int nend = (slice < 4) ? nbeg + 25 : nbeg + 24;
    float a0 = 0.f, a1 = 0.f, a2 = 0.f, a3 = 0.f;
    float a4 = 0.f, a5 = 0.f, a6 = 0.f, a7 = 0.f;
    if (VBF) {
        const ushort* vb = (const ushort*)visp + (size_t)b * NR * DV + c8;
        for (int n = nbeg; n < nend; ++n) {
            const float s = sc[n];
            const uint4 v = *(const uint4*)&vb[(size_t)n * DV];
            a0 = fmaf(s, bf2f((ushort)(v.x & 0xFFFF)), a0);
            a1 = fmaf(s, bf2f((ushort)(v.x >> 16)), a1);
            a2 = fmaf(s, bf2f((ushort)(v.y & 0xFFFF)), a2);
            a3 = fmaf(s, bf2f((ushort)(v.y >> 16)), a3);
            a4 = fmaf(s, bf2f((ushort)(v.z & 0xFFFF)), a4);
            a5 = fmaf(s, bf2f((ushort)(v.z >> 16)), a5);
            a6 = fmaf(s, bf2f((ushort)(v.w & 0xFFFF)), a6);
            a7 = fmaf(s, bf2f((ushort)(v.w >> 16)), a7);
        }
    } else {
        const float* vb = (const float*)visp + (size_t)b * NR * DV + c8;
        for (int n = nbeg; n < nend; ++n) {
            const float s = sc[n];
            const float4 v0 = *(const float4*)&vb[(size_t)n * DV];
            const float4 v1 = *(const float4*)&vb[(size_t)n * DV + 4];
            a0 = fmaf(s, v0.x, a0); a1 = fmaf(s, v0.y, a1);
            a2 = fmaf(s, v0.z, a2); a3 = fmaf(s, v0.w, a3);
            a4 = fmaf(s, v1.x, a4); a5 = fmaf(s, v1.y, a5);
            a6 = fmaf(s, v1.z, a6); a7 = fmaf(s, v1.w, a7);
        }
    }
    float4 av0; av0.x = a0; av0.y = a1; av0.z = a2; av0.w = a3;
    float4 av1; av1.x = a4; av1.y = a5; av1.z = a6; av1.w = a7;
    *(float4*)&part[slice][c8]     = av0;
    *(float4*)&part[slice][c8 + 4] = av1;
    __syncthreads();
    const float v = ((part[0][t] + part[1][t]) + (part[2][t] + part[3][t]))
                  + ((part[4][t] + part[5][t]) + (part[6][t] + part[7][t]));
    const ushort vh16 = f2bf(v);
    att_h[(size_t)b * DV + t] = vh16;
    att_l[(size_t)b * DV + t] = f2bf(v - bf2f(vh16));
}

// ---------------------------------------------------------------------------
// batched final stop projection over all (s,b): row = s*BB + b.
// ---------------------------------------------------------------------------
__global__ __launch_bounds__(256) void stop_final_all(
    const float* __restrict__ pt, const float* __restrict__ fw,
    const float* __restrict__ fb, float* __restrict__ outp)
{
    const int row = blockIdx.x;
    const int s = row >> 8, b = row & 255;
    const int t = threadIdx.x;
    const int lane = t & 63;
    const int w = t >> 6;

    __shared__ float red[16];
    const float v = pt[(size_t)row * IS + t];
    float p0 = v * fw[t];
    float p1 = v * fw[IS + t];
    for (int off = 32; off; off >>= 1) {
        p0 += __shfl_down(p0, off);
        p1 += __shfl_down(p1, off);
    }
    if (lane == 0) { red[w] = p0; red[8 + w] = p1; }
    __syncthreads();
    if (t == 0) {
        outp[((size_t)b * ST + s) * 2 + 0] = red[0] + red[1] + red[2] + red[3] + fb[0];
        outp[((size_t)b * ST + s) * 2 + 1] = red[8] + red[9] + red[10] + red[11] + fb[1];
    }
}

// ---------------------------------------------------------------------------
extern "C" void kernel_launch(void* const* d_in, const int* in_sizes, int n_in,
                              void* d_out, int out_size, void* d_ws, size_t ws_size,
                              hipStream_t stream)
{
    const float* vis        = (const float*)d_in[0];
    const float* enc_att_w  = (const float*)d_in[2];
    const float* enc_att_b  = (const float*)d_in[3];
    const float* dec_att_w  = (const float*)d_in[4];
    const float* dec_att_b  = (const float*)d_in[5];
    const float* full_att_w = (const float*)d_in[6];
    const float* full_att_b = (const float*)d_in[7];
    const float* ctx_w      = (const float*)d_in[8];
    const float* ctx_b      = (const float*)d_in[9];
    const float* W_ih       = (const float*)d_in[10];
    const float* b_ih       = (const float*)d_in[11];
    const float* W_hh       = (const float*)d_in[12];
    const float* b_hh       = (const float*)d_in[13];
    const float* topic_hid_w = (const float*)d_in[14];
    const float* topic_hid_b = (const float*)d_in[15];
    const float* topic_ctx_w = (const float*)d_in[16];
    const float* topic_ctx_b = (const float*)d_in[17];
    const float* stop_prev_w = (const float*)d_in[18];
    const float* stop_prev_b = (const float*)d_in[19];
    const float* stop_cur_w  = (const float*)d_in[20];
    const float* stop_cur_b  = (const float*)d_in[21];
    const float* final_stop_w = (const float*)d_in[22];
    const float* final_stop_b = (const float*)d_in[23];

    float* out_topics = (float*)d_out;                        // [B, ST, WI]
    float* out_ps     = (float*)d_out + (size_t)BB * ST * WI; // [B, ST, 2]

    char* ws = (char*)d_ws;
    size_t off = 0;
    auto alloc = [&](size_t bytes) -> void* {
        void* p = (void*)(ws + off);
        off += (bytes + 255) & ~(size_t)255;
        return p;
    };
    ushort* vis_att = (ushort*)alloc((size_t)BB * NR * AT * 2);      // 25.7 MB
    // split pool: enc(256)+hh(4096)+th(1024)+sp(256)+sc(256)+dec(256)
    //             +W_ih(4096)+topic_ctx(1024) rows
    const size_t WTOT = (size_t)11264 * 1024;
    ushort* wh = (ushort*)alloc(WTOT * 2);                           // 23.1 MB
    ushort* wl = (ushort*)alloc(WTOT * 2);                           // 23.1 MB
    ushort* hh_h   = (ushort*)alloc((size_t)(ST + 1) * BB * HH * 2); // 5.8 MB
    ushort* hh_l   = (ushort*)alloc((size_t)(ST + 1) * BB * HH * 2); // 5.8 MB
    ushort* att_all_h = (ushort*)alloc((size_t)ST * BB * DV * 2);    // 5.25 MB
    ushort* att_all_l = (ushort*)alloc((size_t)ST * BB * DV * 2);    // 5.25 MB
    float* cbuf    = (float*)alloc((size_t)BB * HH * 4);
    float* pt_all  = (float*)alloc((size_t)ST * BB * IS * 4);        // 2.6 MB
    // ctx-fold pools
    ushort* ctT_h  = (ushort*)alloc((size_t)SI * DV * 2);            // 2 MB
    ushort* ctT_l  = (ushort*)alloc((size_t)SI * DV * 2);
    ushort* cmb_h  = (ushort*)alloc((size_t)4 * HH * SI * 2);        // 8.4 MB
    ushort* cmb_l  = (ushort*)alloc((size_t)4 * HH * SI * 2);
    ushort* tcc_h  = (ushort*)alloc((size_t)WI * SI * 2);            // 2 MB
    ushort* tcc_l  = (ushort*)alloc((size_t)WI * SI * 2);
    float* bf_ih   = (float*)alloc((size_t)4 * HH * 4);
    float* bf_tc   = (float*)alloc((size_t)WI * 4);
    if (off > ws_size) return;  // core workspace too small — fail visibly
    // bf16 copy of vis (98 MB); fallback to fp32-A path if no room
    ushort* vis_bf = nullptr;
    {
        const size_t need = (size_t)BB * NR * DV * 2;
        if (off + need <= ws_size) vis_bf = (ushort*)alloc(need);
    }

    // weight segment offsets (elements) within the pool
    const size_t O_ENC = 0;              // 256x1024
    const size_t O_HH  = 262144;         // 4096x1024 (row-interleaved)
    const size_t O_TH  = 4456448;        // 1024x1024
    const size_t O_SP  = 5505024;        // 256x1024
    const size_t O_SC  = 5767168;        // 256x1024
    const size_t O_DEC = 6029312;        // 256x1024 (hi used by att_step)
    const size_t O_IH2 = 6291456;        // 4096x1024 (plain, ws A)
    const size_t O_TC2 = 10485760;       // 1024x1024 (plain, ws A)

    CvtTab tab;
    const float* srcs[8] = {enc_att_w, W_hh, topic_hid_w, stop_prev_w, stop_cur_w,
                            dec_att_w, W_ih, topic_ctx_w};
    const size_t offs[8] = {O_ENC, O_HH, O_TH, O_SP, O_SC, O_DEC, O_IH2, O_TC2};
    for (int i = 0; i < 8; ++i) {
        tab.s[i] = srcs[i];
        tab.h[i] = wh + offs[i];
        tab.l[i] = wl + offs[i];
    }

    hipMemsetAsync(hh_h, 0, (size_t)BB * HH * 2, stream);    // h_0 hi = 0
    hipMemsetAsync(hh_l, 0, (size_t)BB * HH * 2, stream);    // h_0 lo = 0
    hipMemsetAsync(cbuf, 0, (size_t)BB * HH * 4, stream);    // c_0 = 0

    convert_split<<<11264, 256, 0, stream>>>(tab);

    // ---- ctx-fold precompute (pre-split A everywhere) ----
    transpose_split<<<dim3(SI / 32, DV / 32), 256, 0, stream>>>(ctx_w, ctT_h, ctT_l);
    mgemm_wsp<1><<<dim3(SI / 64, 4 * HH / 64), 256, 0, stream>>>(
        wh + O_IH2, wl + O_IH2, ctT_h, ctT_l, cmb_h, cmb_l, SI, DV);
    mgemm_wsp<0><<<dim3(SI / 64, WI / 64), 256, 0, stream>>>(
        wh + O_TC2, wl + O_TC2, ctT_h, ctT_l, tcc_h, tcc_l, SI, DV);
    foldbias2<<<1280, 256, 0, stream>>>(W_ih, topic_ctx_w, ctx_b,
                                        b_ih, topic_ctx_b, bf_ih, bf_tc);

    // hoisted encoder projection (split conversion + GEMM — measured best)
    convert_vis<<<(BB * NR * DV) / (256 * 8), 256, 0, stream>>>(vis, vis_bf);
    mgemm_preb<<<(BB * NR) / 128, 512, 0, stream>>>(
        vis_bf, wh + O_ENC, wl + O_ENC, enc_att_b, vis_att);

    for (int s = 0; s < ST; ++s) {
        ushort* hch = hh_h + (size_t)s * BB * HH;
        ushort* hcl = hh_l + (size_t)s * BB * HH;
        ushort* hnh = hh_h + (size_t)(s + 1) * BB * HH;
        ushort* hnl = hh_l + (size_t)(s + 1) * BB * HH;
        ushort* ath = att_all_h + (size_t)s * BB * DV;
        ushort* atl = att_all_l + (size_t)s * BB * DV;
        // fused dec(bf16 w, h from hi+lo) + logits + softmax + apply
        att_step<1><<<BB, 1024, 0, stream>>>(vis_att, hch, hcl, wh + O_DEC, dec_att_b,
                                             full_att_w, full_att_b, vis_bf,
                                             ath, atl);
        // gates = att @ W_comb^T + bf_ih + h @ W_hh^T + b_hh, fused LSTM
        mgemm8_lstm<<<dim3(4 * HH / 32, BB / 64), 512, 0, stream>>>(
            ath, atl, cmb_h, cmb_l, bf_ih,
            hch, hcl, wh + O_HH, wl + O_HH, b_hh,
            SI, cbuf, hnh, hnl);
    }

    // deferred heads: topic (640 blocks) + stop (160 blocks) in ONE dispatch
    mgemm_heads<<<800, 256, 0, stream>>>(
        hh_h + (size_t)BB * HH, hh_l + (size_t)BB * HH,
        wh + O_TH, wl + O_TH, topic_hid_b,
        att_all_h, att_all_l, tcc_h, tcc_l, bf_tc,
        out_topics,
        hh_h, hh_l, wh + O_SP, wl + O_SP, stop_prev_b,
        hh_h + (size_t)BB * HH, hh_l + (size_t)BB * HH,
        wh + O_SC, wl + O_SC, stop_cur_b,
        pt_all);
    stop_final_all<<<ST * BB, 256, 0, stream>>>(pt_all, final_stop_w, final_stop_b, out_ps);
}

// Round 24
// 955.552 us; speedup vs baseline: 1.0437x; 1.0067x over previous
//
#include <hip/hip_runtime.h>
#include <hip/hip_bf16.h>
#include <math.h>

// Problem constants (SentenceLSTM)
static constexpr int BB = 256;    // batch
static constexpr int NR = 196;    // regions
static constexpr int DV = 1024;   // vis embed dim
static constexpr int HH = 1024;   // hidden
static constexpr int AT = 256;    // att dim
static constexpr int SI = 1024;   // sem input dim (ctx)
static constexpr int WI = 1024;   // topic width
static constexpr int IS = 256;    // stop inner dim
static constexpr int ST = 10;     // sentence steps

__device__ __forceinline__ float sigmoidf_(float x) { return 1.0f / (1.0f + expf(-x)); }

// bf16 round-to-nearest-even, bit-level
__device__ __forceinline__ ushort f2bf(float x) {
    uint u = __float_as_uint(x);
    return (ushort)((u + 0x7FFFu + ((u >> 16) & 1u)) >> 16);
}
__device__ __forceinline__ float bf2f(ushort b) { return __uint_as_float(((uint)b) << 16); }

using bf16x8 = __attribute__((ext_vector_type(8))) short;
using f32x4  = __attribute__((ext_vector_type(4))) float;
#define MFMA_B16(a, b, c) __builtin_amdgcn_mfma_f32_16x16x32_bf16((a), (b), (c), 0, 0, 0)

// ---------------------------------------------------------------------------
// Weight fp32 -> (hi,lo) bf16 split conversion. LIVE segments:
// 0:enc 1:W_hh(row-interleaved: r' = (r&1023)*4 + (r>>10)) 2:th 3:sp 4:sc
// 5:dec_att (hi only — lo is never consumed) 6:W_ih(plain) 7:topic_ctx(plain).
// ---------------------------------------------------------------------------
struct CvtTab { const float* s[8]; ushort* h[8]; ushort* l[8]; };

__global__ __launch_bounds__(256) void convert_split(CvtTab tab) {
    const int cum[9] = {0, 256, 4352, 5376, 5632, 5888, 6144, 10240, 11264};
    const int bid = blockIdx.x;
    int seg = 0;
#pragma unroll
    for (int i = 1; i < 8; ++i) if (bid >= cum[i]) seg = i;
    const float* s = tab.s[seg];
    ushort* h = tab.h[seg];
    ushort* l = tab.l[seg];
    const int r = bid - cum[seg];
    int rd = r;
    if (seg == 1) rd = (r & 1023) * 4 + (r >> 10);
    const int src = r * 1024 + threadIdx.x * 4;
    const size_t dst = (size_t)rd * 1024 + threadIdx.x * 4;
    float4 v = *(const float4*)(s + src);
    ushort h0 = f2bf(v.x), h1 = f2bf(v.y), h2 = f2bf(v.z), h3 = f2bf(v.w);
    uint2 hq;
    hq.x = h0 | ((uint)h1 << 16); hq.y = h2 | ((uint)h3 << 16);
    *(uint2*)(h + dst) = hq;
    if (seg != 5) {   // dec_att lo is dead — skip its math and store
        uint2 lq;
        ushort l0 = f2bf(v.x - bf2f(h0)), l1 = f2bf(v.y - bf2f(h1));
        ushort l2 = f2bf(v.z - bf2f(h2)), l3 = f2bf(v.w - bf2f(h3));
        lq.x = l0 | ((uint)l1 << 16); lq.y = l2 | ((uint)l3 << 16);
        *(uint2*)(l + dst) = lq;
    }
}

// ---------------------------------------------------------------------------
// convert_vis: vh = bf16(vis). 8 elems/thread, pure streaming.
// ---------------------------------------------------------------------------
__global__ __launch_bounds__(256) void convert_vis(
    const float* __restrict__ src, ushort* __restrict__ dst)
{
    const size_t i = ((size_t)blockIdx.x * 256 + threadIdx.x) * 8;
    const float4 v0 = *(const float4*)(src + i);
    const float4 v1 = *(const float4*)(src + i + 4);
    uint4 o;
    o.x = f2bf(v0.x) | ((uint)f2bf(v0.y) << 16);
    o.y = f2bf(v0.z) | ((uint)f2bf(v0.w) << 16);
    o.z = f2bf(v1.x) | ((uint)f2bf(v1.y) << 16);
    o.w = f2bf(v1.z) | ((uint)f2bf(v1.w) << 16);
    *(uint4*)(dst + i) = o;
}

// ---------------------------------------------------------------------------
// transpose_split: dh/dl = split(src^T) for src [1024,1024] fp32.
// ---------------------------------------------------------------------------
__global__ __launch_bounds__(256) void transpose_split(
    const float* __restrict__ src, ushort* __restrict__ dh, ushort* __restrict__ dl)
{
    __shared__ float T[32][33];
    const int tx = threadIdx.x & 31, ty = threadIdx.x >> 5;
    const int k0 = blockIdx.x * 32, n0 = blockIdx.y * 32;
#pragma unroll
    for (int j = 0; j < 4; ++j)
        T[ty + 8 * j][tx] = src[(size_t)(k0 + ty + 8 * j) * 1024 + n0 + tx];
    __syncthreads();
#pragma unroll
    for (int j = 0; j < 4; ++j) {
        const float v = T[tx][ty + 8 * j];
        const ushort h = f2bf(v);
        const size_t o = (size_t)(n0 + ty + 8 * j) * 1024 + k0 + tx;
        dh[o] = h;
        dl[o] = f2bf(v - bf2f(h));
    }
}

// ---------------------------------------------------------------------------
// foldbias2: merged bias folding for both heads.
// blocks 0..1023: bf_ih[n] = dot(W_ih[n], ctx_b) + b_ih[n]
// blocks 1024..1279: bf_tc[n] = dot(topic_ctx_w[n], ctx_b) + topic_ctx_b[n]
// ---------------------------------------------------------------------------
__global__ __launch_bounds__(256) void foldbias2(
    const float* __restrict__ Wih, const float* __restrict__ Wtc,
    const float* __restrict__ v,
    const float* __restrict__ bih, const float* __restrict__ btc,
    float* __restrict__ out_ih, float* __restrict__ out_tc)
{
    const int bid = blockIdx.x;
    const int lane = threadIdx.x & 63;
    const float* W; const float* b; float* out; int n;
    if (bid < 1024) { W = Wih; b = bih; out = out_ih; n = bid * 4 + (threadIdx.x >> 6); }
    else { W = Wtc; b = btc; out = out_tc; n = (bid - 1024) * 4 + (threadIdx.x >> 6); }
    const float* wr = W + (size_t)n * 1024;
    float p = 0.f;
#pragma unroll
    for (int i = 0; i < 4; ++i) {
        const float4 wv = *(const float4*)&wr[i * 256 + lane * 4];
        const float4 vv = *(const float4*)&v[i * 256 + lane * 4];
        p = fmaf(wv.x, vv.x, p); p = fmaf(wv.y, vv.y, p);
        p = fmaf(wv.z, vv.z, p); p = fmaf(wv.w, vv.w, p);
    }
    for (int off = 32; off; off >>= 1) p += __shfl_down(p, off);
    if (lane == 0) out[n] = p + b[n];
}

// ---------------------------------------------------------------------------
// mgemm_wsp2: MERGED weight synthesis, pre-split A, shared B = ctx_w^T.
// 1280 blocks: bid < 1024 -> A=W_ih (4096x1024), C=cmb, ILV row remap;
//              bid >= 1024 -> A=topic_ctx_w (1024x1024), C=tcc, plain rows.
// Csplit = A @ W^T, N=SI, K=DV for both.
// ---------------------------------------------------------------------------
__global__ __launch_bounds__(256) void mgemm_wsp2(
    const ushort* __restrict__ A1h, const ushort* __restrict__ A1l,
    ushort* __restrict__ C1h, ushort* __restrict__ C1l,
    const ushort* __restrict__ A2h, const ushort* __restrict__ A2l,
    ushort* __restrict__ C2h, ushort* __restrict__ C2l,
    const ushort* __restrict__ Wh, const ushort* __restrict__ Wl)
{
    __shared__ __align__(16) ushort SM[4 * 64 * 40];
    ushort* Ah = SM; ushort* Al = SM + 2560; ushort* Bh = SM + 5120; ushort* Bl = SM + 7680;

    const int bid = blockIdx.x;
    const int seg1 = (bid < 1024) ? 1 : 0;
    const int lb = seg1 ? bid : (bid - 1024);
    const int bx = lb & 15, by = lb >> 4;
    const int m0 = by * 64, n0 = bx * 64;
    const ushort* Ahg = seg1 ? A1h : A2h;
    const ushort* Alg = seg1 ? A1l : A2l;
    ushort* Ch = seg1 ? C1h : C2h;
    ushort* Cl = seg1 ? C1l : C2l;
    const int N = SI, K = DV;

    const int t = threadIdx.x;
    const int w = t >> 6, lane = t & 63;
    const int l15 = lane & 15, q = lane >> 4;
    const int sr = t >> 2, sq = (t & 3) * 8;
    const int nch = K >> 5;

    f32x4 acc[4] = {};
    uint4 pah, pal, pbh, pbl;
    auto pref = [&](int c) {
        const int k0 = c << 5;
        const size_t ab = (size_t)(m0 + sr) * K + k0 + sq;
        pah = *(const uint4*)&Ahg[ab];
        pal = *(const uint4*)&Alg[ab];
        pbh = *(const uint4*)&Wh[(size_t)(n0 + sr) * K + k0 + sq];
        pbl = *(const uint4*)&Wl[(size_t)(n0 + sr) * K + k0 + sq];
    };
    pref(0);

    for (int c = 0; c < nch; ++c) {
        __syncthreads();
        *(uint4*)&Ah[sr * 40 + sq] = pah;
        *(uint4*)&Al[sr * 40 + sq] = pal;
        *(uint4*)&Bh[sr * 40 + sq] = pbh;
        *(uint4*)&Bl[sr * 40 + sq] = pbl;
        __syncthreads();
        if (c + 1 < nch) pref(c + 1);
        const bf16x8 bh = *(const bf16x8*)&Bh[(w * 16 + l15) * 40 + q * 8];
        const bf16x8 bl = *(const bf16x8*)&Bl[(w * 16 + l15) * 40 + q * 8];
#pragma unroll
        for (int mi = 0; mi < 4; ++mi) {
            const bf16x8 ah = *(const bf16x8*)&Ah[(mi * 16 + l15) * 40 + q * 8];
            const bf16x8 al = *(const bf16x8*)&Al[(mi * 16 + l15) * 40 + q * 8];
            acc[mi] = MFMA_B16(ah, bh, acc[mi]);
            acc[mi] = MFMA_B16(ah, bl, acc[mi]);
            acc[mi] = MFMA_B16(al, bh, acc[mi]);
        }
    }

    const int col = n0 + w * 16 + l15;
#pragma unroll
    for (int mi = 0; mi < 4; ++mi) {
#pragma unroll
        for (int j = 0; j < 4; ++j) {
            const int row = m0 + mi * 16 + q * 4 + j;
            const int ro = seg1 ? ((row & 1023) * 4 + (row >> 10)) : row;
            const float v = acc[mi][j];
            const ushort h = f2bf(v);
            Ch[(size_t)ro * N + col] = h;
            Cl[(size_t)ro * N + col] = f2bf(v - bf2f(h));
        }
    }
}

// ---------------------------------------------------------------------------
// mgemm_heads: MERGED deferred-head GEMM. 800 blocks, 1D:
//   bid <  640: topic tile (bx=bid&15, by=bid>>4), OMAP row remap, ldc=WI
//   bid >= 640: stop  tile (bx=(bid-640)&3, by=(bid-640)>>2), ldc=IS
// Both: C = tanh(A1*W1^T + A2*W2^T + b1+b2), K=1024, pre-split operands.
// ---------------------------------------------------------------------------
__global__ __launch_bounds__(256) void mgemm_heads(
    const ushort* __restrict__ tA1h, const ushort* __restrict__ tA1l,
    const ushort* __restrict__ tW1h, const ushort* __restrict__ tW1l,
    const float* __restrict__ tb1,
    const ushort* __restrict__ tA2h, const ushort* __restrict__ tA2l,
    const ushort* __restrict__ tW2h, const ushort* __restrict__ tW2l,
    const float* __restrict__ tb2,
    float* __restrict__ tC,
    const ushort* __restrict__ sA1h, const ushort* __restrict__ sA1l,
    const ushort* __restrict__ sW1h, const ushort* __restrict__ sW1l,
    const float* __restrict__ sb1,
    const ushort* __restrict__ sA2h, const ushort* __restrict__ sA2l,
    const ushort* __restrict__ sW2h, const ushort* __restrict__ sW2l,
    const float* __restrict__ sb2,
    float* __restrict__ sC)
{
    __shared__ __align__(16) ushort SM[4 * 64 * 40];
    ushort* Ah = SM; ushort* Al = SM + 2560; ushort* Bh = SM + 5120; ushort* Bl = SM + 7680;

    const int bid = blockIdx.x;
    const int topic = (bid < 640) ? 1 : 0;
    const int lb = topic ? bid : (bid - 640);
    const int bx = topic ? (lb & 15) : (lb & 3);
    const int by = topic ? (lb >> 4) : (lb >> 2);
    const int m0 = by * 64, n0 = bx * 64;
    const int ldc = topic ? WI : IS;

    const ushort* A1h = topic ? tA1h : sA1h;  const ushort* A1l = topic ? tA1l : sA1l;
    const ushort* W1h = topic ? tW1h : sW1h;  const ushort* W1l = topic ? tW1l : sW1l;
    const float*  b1  = topic ? tb1  : sb1;
    const ushort* A2h = topic ? tA2h : sA2h;  const ushort* A2l = topic ? tA2l : sA2l;
    const ushort* W2h = topic ? tW2h : sW2h;  const ushort* W2l = topic ? tW2l : sW2l;
    const float*  b2  = topic ? tb2  : sb2;
    float* C = topic ? tC : sC;

    const int t = threadIdx.x;
    const int w = t >> 6, lane = t & 63;
    const int l15 = lane & 15, q = lane >> 4;
    const int sr = t >> 2, sq = (t & 3) * 8;
    const int K = HH;
    const int KC = K >> 5, nch = 2 * KC;

    f32x4 acc[4] = {};
    uint4 pah, pal, pbh, pbl;

    auto pref = [&](int c) {
        const int pass = (c >= KC) ? 1 : 0;
        const int k0 = (c - pass * KC) << 5;
        const ushort* Axh = pass ? A2h : A1h;
        const ushort* Axl = pass ? A2l : A1l;
        const ushort* Wh = pass ? W2h : W1h;
        const ushort* Wl = pass ? W2l : W1l;
        const size_t ab = (size_t)(m0 + sr) * K + k0 + sq;
        pah = *(const uint4*)&Axh[ab];
        pal = *(const uint4*)&Axl[ab];
        pbh = *(const uint4*)&Wh[(size_t)(n0 + sr) * K + k0 + sq];
        pbl = *(const uint4*)&Wl[(size_t)(n0 + sr) * K + k0 + sq];
    };
    pref(0);

    for (int c = 0; c < nch; ++c) {
        __syncthreads();
        *(uint4*)&Ah[sr * 40 + sq] = pah;
        *(uint4*)&Al[sr * 40 + sq] = pal;
        *(uint4*)&Bh[sr * 40 + sq] = pbh;
        *(uint4*)&Bl[sr * 40 + sq] = pbl;
        __syncthreads();
        if (c + 1 < nch) pref(c + 1);
        const bf16x8 bh = *(const bf16x8*)&Bh[(w * 16 + l15) * 40 + q * 8];
        const bf16x8 bl = *(const bf16x8*)&Bl[(w * 16 + l15) * 40 + q * 8];
#pragma unroll
        for (int mi = 0; mi < 4; ++mi) {
            const bf16x8 ah = *(const bf16x8*)&Ah[(mi * 16 + l15) * 40 + q * 8];
            const bf16x8 al = *(const bf16x8*)&Al[(mi * 16 + l15) * 40 + q * 8];
            acc[mi] = MFMA_B16(ah, bh, acc[mi]);
            acc[mi] = MFMA_B16(ah, bl, acc[mi]);
            acc[mi] = MFMA_B16(al, bh, acc[mi]);
        }
    }

    const int col = n0 + w * 16 + l15;
    const float bias = b1[col] + b2[col];
#pragma unroll
    for (int mi = 0; mi < 4; ++mi) {
#pragma unroll
        for (int j = 0; j < 4; ++j) {
            const int row = m0 + mi * 16 + q * 4 + j;
            const float v = tanhf(acc[mi][j] + bias);
            if (topic)
                C[((size_t)(row & 255) * ST + (row >> 8)) * ldc + col] = v;
            else
                C[(size_t)row * ldc + col] = v;
        }
    }
}

// ---------------------------------------------------------------------------
// mgemm8_lstm: BK=64 body, pre-split activations; B-staging stride 64 with
// XOR swizzle; comb/G aliased into group-1 staging. LDS 53248 B.
// h state kept ONLY as hi/lo bf16 (no fp32 h write).
// ---------------------------------------------------------------------------
__global__ __launch_bounds__(512, 6) void mgemm8_lstm(
    const ushort* __restrict__ A1h, const ushort* __restrict__ A1l,
    const ushort* __restrict__ W1h, const ushort* __restrict__ W1l,
    const float* __restrict__ b1,
    const ushort* __restrict__ A2h, const ushort* __restrict__ A2l,
    const ushort* __restrict__ W2h, const ushort* __restrict__ W2l,
    const float* __restrict__ b2,
    int K, float* __restrict__ cvec,
    ushort* __restrict__ hnh, ushort* __restrict__ hnl)
{
    __shared__ __align__(16) ushort SM[26624];   // 53248 B

    const int t = threadIdx.x;
    const int m0 = blockIdx.y * 64, n0 = blockIdx.x * 32;
    const int w = t >> 6, lane = t & 63;
    const int g = w >> 2, wg = w & 3;
    const int l15 = lane & 15, q = lane >> 4;
    const int tl = t & 255;
    const int sr = tl >> 2, sq4 = (tl & 3) * 16;
    const int br = tl >> 3, bq = (tl & 7) * 8;
    const int mh = wg >> 1;
    const int colL = (wg & 1) * 16 + l15;

    ushort* Ah = SM + g * 13312;
    ushort* Al = Ah + 4608;
    ushort* Bh = Al + 4608;
    ushort* Bl = Bh + 2048;

    const int nchg = K >> 6;
    const ushort* Ahg = g ? A2h : A1h;
    const ushort* Alg = g ? A2l : A1l;
    const ushort* Wh  = g ? W2h : W1h;
    const ushort* Wl  = g ? W2l : W1l;

    const int bwi = br * 64 + (bq ^ ((br & 7) << 3));

    f32x4 acc[2] = {};
    uint4 pah0, pah1, pal0, pal1, pbh, pbl;
    auto pref = [&](int c) {
        const int k0 = c << 6;
        const size_t ab = (size_t)(m0 + sr) * K + k0 + sq4;
        pah0 = *(const uint4*)&Ahg[ab];
        pah1 = *(const uint4*)&Ahg[ab + 8];
        pal0 = *(const uint4*)&Alg[ab];
        pal1 = *(const uint4*)&Alg[ab + 8];
        pbh = *(const uint4*)&Wh[(size_t)(n0 + br) * K + k0 + bq];
        pbl = *(const uint4*)&Wl[(size_t)(n0 + br) * K + k0 + bq];
    };
    pref(0);

    for (int c = 0; c < nchg; ++c) {
        __syncthreads();
        *(uint4*)&Ah[sr * 72 + sq4]     = pah0;
        *(uint4*)&Ah[sr * 72 + sq4 + 8] = pah1;
        *(uint4*)&Al[sr * 72 + sq4]     = pal0;
        *(uint4*)&Al[sr * 72 + sq4 + 8] = pal1;
        *(uint4*)&Bh[bwi] = pbh;
        *(uint4*)&Bl[bwi] = pbl;
        __syncthreads();
        if (c + 1 < nchg) pref(c + 1);
#pragma unroll
        for (int ks = 0; ks < 2; ++ks) {
            const int bro = colL * 64 + ((ks * 32 + q * 8) ^ ((colL & 7) << 3));
            const bf16x8 bh = *(const bf16x8*)&Bh[bro];
            const bf16x8 bl = *(const bf16x8*)&Bl[bro];
#pragma unroll
            for (int i = 0; i < 2; ++i) {
                const int mi = mh * 2 + i;
                const bf16x8 ah = *(const bf16x8*)&Ah[(mi * 16 + l15) * 72 + ks * 32 + q * 8];
                const bf16x8 al = *(const bf16x8*)&Al[(mi * 16 + l15) * 72 + ks * 32 + q * 8];
                acc[i] = MFMA_B16(ah, bh, acc[i]);
                acc[i] = MFMA_B16(ah, bl, acc[i]);
                acc[i] = MFMA_B16(al, bh, acc[i]);
            }
        }
    }

    // combine group-1 partials into group-0
    float* comb = (float*)(SM + 13312);
    __syncthreads();
    if (g == 1) {
#pragma unroll
        for (int i = 0; i < 2; ++i)
#pragma unroll
            for (int j = 0; j < 4; ++j) comb[tl * 9 + i * 4 + j] = acc[i][j];
    }
    __syncthreads();
    if (g == 0) {
#pragma unroll
        for (int i = 0; i < 2; ++i)
#pragma unroll
            for (int j = 0; j < 4; ++j) acc[i][j] += comb[tl * 9 + i * 4 + j];
    }

    // LSTM pointwise. Gate cols interleaved (col' = unit*4+gate).
    float* G = (float*)(SM + 17920);
    if (g == 0) {
        const int colG = n0 + colL;
        const int gate = colG & 3, unit = colG >> 2;
        const float bias = b1[gate * 1024 + unit] + b2[gate * 1024 + unit];
#pragma unroll
        for (int i = 0; i < 2; ++i) {
            const int mi = mh * 2 + i;
#pragma unroll
            for (int j = 0; j < 4; ++j)
                G[(mi * 16 + q * 4 + j) * 40 + colL] = acc[i][j] + bias;
        }
    }
    __syncthreads();
    {
        const int row = t >> 3, ul = t & 7;
        const float4 g4 = *(const float4*)&G[row * 40 + ul * 4];  // i,f,g,o
        const size_t ci = (size_t)(m0 + row) * HH + (n0 >> 2) + ul;
        const float cn = sigmoidf_(g4.y) * cvec[ci] + sigmoidf_(g4.x) * tanhf(g4.z);
        cvec[ci] = cn;
        const float hv = sigmoidf_(g4.w) * tanhf(cn);
        const ushort hhi = f2bf(hv);
        hnh[ci] = hhi;
        hnl[ci] = f2bf(hv - bf2f(hhi));
    }
}

// ---------------------------------------------------------------------------
// mgemm_preb: vis_att(bf16) = vh(bf16) @ enc^T + b, 2-term (A-hi only,
// B hi+lo). Tile 128M x 256N, 512 threads, BK=32, reg prefetch after barrier.
// ---------------------------------------------------------------------------
__global__ __launch_bounds__(512) void mgemm_preb(
    const ushort* __restrict__ vh, const ushort* __restrict__ Wh, const ushort* __restrict__ Wl,
    const float* __restrict__ bias, ushort* __restrict__ C)
{
    __shared__ __align__(16) ushort Avh[128 * 40];
    __shared__ __align__(16) ushort Bh[256 * 40];
    __shared__ __align__(16) ushort Bl[256 * 40];

    const int t = threadIdx.x;
    const int m0 = blockIdx.x * 128;
    const int w = t >> 6, lane = t & 63;
    const int rg = w >> 2, cg = w & 3;
    const int l15 = lane & 15, q = lane >> 4;
    const int ar = t >> 2, ac = (t & 3) * 8;
    const int brr = t >> 1, bc = (t & 1) * 16;
    const int K = DV;

    f32x4 acc[4][4] = {};
    uint4 pa, pbh0, pbh1, pbl0, pbl1;
    auto pref = [&](int c) {
        const int k0 = c << 5;
        pa   = *(const uint4*)&vh[(size_t)(m0 + ar) * K + k0 + ac];
        const size_t bb = (size_t)brr * K + k0 + bc;
        pbh0 = *(const uint4*)&Wh[bb];
        pbh1 = *(const uint4*)&Wh[bb + 8];
        pbl0 = *(const uint4*)&Wl[bb];
        pbl1 = *(const uint4*)&Wl[bb + 8];
    };
    pref(0);

    for (int c = 0; c < 32; ++c) {
        __syncthreads();
        *(uint4*)&Avh[ar * 40 + ac] = pa;
        *(uint4*)&Bh[brr * 40 + bc]     = pbh0;
        *(uint4*)&Bh[brr * 40 + bc + 8] = pbh1;
        *(uint4*)&Bl[brr * 40 + bc]     = pbl0;
        *(uint4*)&Bl[brr * 40 + bc + 8] = pbl1;
        __syncthreads();
        if (c + 1 < 32) pref(c + 1);

        bf16x8 ah[4];
#pragma unroll
        for (int mi = 0; mi < 4; ++mi)
            ah[mi] = *(const bf16x8*)&Avh[(rg * 64 + mi * 16 + l15) * 40 + q * 8];
#pragma unroll
        for (int ni = 0; ni < 4; ++ni) {
            const bf16x8 bh = *(const bf16x8*)&Bh[(cg * 64 + ni * 16 + l15) * 40 + q * 8];
            const bf16x8 bl = *(const bf16x8*)&Bl[(cg * 64 + ni * 16 + l15) * 40 + q * 8];
#pragma unroll
            for (int mi = 0; mi < 4; ++mi) {
                acc[mi][ni] = MFMA_B16(ah[mi], bh, acc[mi][ni]);
                acc[mi][ni] = MFMA_B16(ah[mi], bl, acc[mi][ni]);
            }
        }
    }

#pragma unroll
    for (int ni = 0; ni < 4; ++ni) {
        const int col = cg * 64 + ni * 16 + l15;
        const float bb = bias[col];
#pragma unroll
        for (int mi = 0; mi < 4; ++mi)
#pragma unroll
            for (int j = 0; j < 4; ++j) {
                const int row = m0 + rg * 64 + mi * 16 + q * 4 + j;
                C[(size_t)row * AT + col] = f2bf(acc[mi][ni][j] + bb);
            }
    }
}

// ---------------------------------------------------------------------------
// att_step: per batch row b (one 1024-thread block): dec(bf16 weights,
// h reconstructed from hi/lo) + logits + softmax + apply. Emits hi/lo att.
// ---------------------------------------------------------------------------
template <int VBF>
__global__ __launch_bounds__(1024) void att_step(
    const ushort* __restrict__ vis_att,
    const ushort* __restrict__ hch, const ushort* __restrict__ hcl,
    const ushort* __restrict__ dec_wh, const float* __restrict__ dec_b,
    const float* __restrict__ fw, const float* __restrict__ fbp,
    const void* __restrict__ visp,
    ushort* __restrict__ att_h, ushort* __restrict__ att_l)
{
    const int b = blockIdx.x;
    const int t = threadIdx.x;
    const int lane = t & 63;
    const int w = t >> 6;

    __shared__ float hs[HH];
    __shared__ float decs[AT];
    __shared__ float fwv[AT];
    __shared__ float logit[NR + 4];
    __shared__ float sc[NR + 4];
    __shared__ float red[8];
    __shared__ float part[8][DV];

    hs[t] = bf2f(hch[(size_t)b * HH + t]) + bf2f(hcl[(size_t)b * HH + t]);
    if (t < AT) fwv[t] = fw[t];
    __syncthreads();
    const float fb = fbp[0];

    // phase 0: dec — bf16(hi) weights, 16B loads. Wave w owns a = w*16..+15.
#pragma unroll
    for (int j = 0; j < 16; ++j) {
        const int a = w * 16 + j;
        const ushort* wr = dec_wh + (size_t)a * HH;
        float p = 0.f;
#pragma unroll
        for (int i = 0; i < 2; ++i) {
            const uint4 wv = *(const uint4*)&wr[i * 512 + lane * 8];
            const float4 hv0 = *(const float4*)&hs[i * 512 + lane * 8];
            const float4 hv1 = *(const float4*)&hs[i * 512 + lane * 8 + 4];
            p = fmaf(bf2f((ushort)(wv.x & 0xFFFF)), hv0.x, p);
            p = fmaf(bf2f((ushort)(wv.x >> 16)),    hv0.y, p);
            p = fmaf(bf2f((ushort)(wv.y & 0xFFFF)), hv0.z, p);
            p = fmaf(bf2f((ushort)(wv.y >> 16)),    hv0.w, p);
            p = fmaf(bf2f((ushort)(wv.z & 0xFFFF)), hv1.x, p);
            p = fmaf(bf2f((ushort)(wv.z >> 16)),    hv1.y, p);
            p = fmaf(bf2f((ushort)(wv.w & 0xFFFF)), hv1.z, p);
            p = fmaf(bf2f((ushort)(wv.w >> 16)),    hv1.w, p);
        }
        for (int off = 32; off; off >>= 1) p += __shfl_down(p, off);
        if (lane == 0) decs[a] = p + dec_b[a];
    }
    __syncthreads();

    // phase 1: logits
    for (int n = w; n < NR; n += 16) {
        const ushort4 v4 = *(const ushort4*)&vis_att[((size_t)b * NR + n) * AT + lane * 4];
        const int a = lane * 4;
        float s = tanhf(bf2f(v4.x) + decs[a]) * fwv[a];
        s = fmaf(tanhf(bf2f(v4.y) + decs[a + 1]), fwv[a + 1], s);
        s = fmaf(tanhf(bf2f(v4.z) + decs[a + 2]), fwv[a + 2], s);
        s = fmaf(tanhf(bf2f(v4.w) + decs[a + 3]), fwv[a + 3], s);
        for (int off = 32; off; off >>= 1) s += __shfl_down(s, off);
        if (lane == 0) logit[n] = s + fb;
    }
    __syncthreads();

    // phase 2: softmax
    float m = -1e30f, e = 0.f;
    if (t < NR) m = logit[t];
    if (t < 256) {
        for (int off = 32; off; off >>= 1) m = fmaxf(m, __shfl_down(m, off));
        if (lane == 0) red[w] = m;
    }
    __syncthreads();
    m = fmaxf(fmaxf(red[0], red[1]), fmaxf(red[2], red[3]));
    if (t < NR) e = expf(logit[t] - m);
    if (t < 256) {
        float ss = e;
        for (int off = 32; off; off >>= 1) ss += __shfl_down(ss, off);
        if (lane == 0) red[4 + w] = ss;
    }
    __syncthreads();
    const float S = red[4] + red[5] + red[6] + red[7];
    if (t < NR) sc[t] = e / S;
    __syncthreads();

    // phase 3: apply — 8-way region split (25,25,25,25,24,24,24,24)
    const int slice = t >> 7;
    const int c8 = (t & 127) * 8;
    const int nbeg = (slice <= 4) ? 25 * slice : 100 + 24 * (slice - 4);
    const int nend = (slice < 4) ? nbeg + 25 : nbeg + 24;
    float a0 = 0.f, a1 = 0.f, a2 = 0.f, a3 = 0.f;
    float a4 = 0.f, a5 = 0.f, a6 = 0.f, a7 = 0.f;
    if (VBF) {
        const ushort* vb = (const ushort*)visp + (size_t)b * NR * DV + c8;
        for (int n = nbeg; n < nend; ++n) {
            const float s = sc[n];
            const uint4 v = *(const uint4*)&vb[(size_t)n * DV];
            a0 = fmaf(s, bf2f((ushort)(v.x & 0xFFFF)), a0);
            a1 = fmaf(s, bf2f((ushort)(v.x >> 16)), a1);
            a2 = fmaf(s, bf2f((ushort)(v.y & 0xFFFF)), a2);
            a3 = fmaf(s, bf2f((ushort)(v.y >> 16)), a3);
            a4 = fmaf(s, bf2f((ushort)(v.z & 0xFFFF)), a4);
            a5 = fmaf(s, bf2f((ushort)(v.z >> 16)), a5);
            a6 = fmaf(s, bf2f((ushort)(v.w & 0xFFFF)), a6);
            a7 = fmaf(s, bf2f((ushort)(v.w >> 16)), a7);
        }
    } else {
        const float* vb = (const float*)visp + (size_t)b * NR * DV + c8;
        for (int n = nbeg; n < nend; ++n) {
            const float s = sc[n];
            const float4 v0 = *(const float4*)&vb[(size_t)n * DV];
            const float4 v1 = *(const float4*)&vb[(size_t)n * DV + 4];
            a0 = fmaf(s, v0.x, a0); a1 = fmaf(s, v0.y, a1);
            a2 = fmaf(s, v0.z, a2); a3 = fmaf(s, v0.w, a3);
            a4 = fmaf(s, v1.x, a4); a5 = fmaf(s, v1.y, a5);
            a6 = fmaf(s, v1.z, a6); a7 = fmaf(s, v1.w, a7);
        }
    }
    float4 av0; av0.x = a0; av0.y = a1; av0.z = a2; av0.w = a3;
    float4 av1; av1.x = a4; av1.y = a5; av1.z = a6; av1.w = a7;
    *(float4*)&part[slice][c8]     = av0;
    *(float4*)&part[slice][c8 + 4] = av1;
    __syncthreads();
    const float v = ((part[0][t] + part[1][t]) + (part[2][t] + part[3][t]))
                  + ((part[4][t] + part[5][t]) + (part[6][t] + part[7][t]));
    const ushort vh16 = f2bf(v);
    att_h[(size_t)b * DV + t] = vh16;
    att_l[(size_t)b * DV + t] = f2bf(v - bf2f(vh16));
}

// ---------------------------------------------------------------------------
// batched final stop projection over all (s,b): row = s*BB + b.
// ---------------------------------------------------------------------------
__global__ __launch_bounds__(256) void stop_final_all(
    const float* __restrict__ pt, const float* __restrict__ fw,
    const float* __restrict__ fb, float* __restrict__ outp)
{
    const int row = blockIdx.x;
    const int s = row >> 8, b = row & 255;
    const int t = threadIdx.x;
    const int lane = t & 63;
    const int w = t >> 6;

    __shared__ float red[16];
    const float v = pt[(size_t)row * IS + t];
    float p0 = v * fw[t];
    float p1 = v * fw[IS + t];
    for (int off = 32; off; off >>= 1) {
        p0 += __shfl_down(p0, off);
        p1 += __shfl_down(p1, off);
    }
    if (lane == 0) { red[w] = p0; red[8 + w] = p1; }
    __syncthreads();
    if (t == 0) {
        outp[((size_t)b * ST + s) * 2 + 0] = red[0] + red[1] + red[2] + red[3] + fb[0];
        outp[((size_t)b * ST + s) * 2 + 1] = red[8] + red[9] + red[10] + red[11] + fb[1];
    }
}

// ---------------------------------------------------------------------------
extern "C" void kernel_launch(void* const* d_in, const int* in_sizes, int n_in,
                              void* d_out, int out_size, void* d_ws, size_t ws_size,
                              hipStream_t stream)
{
    const float* vis        = (const float*)d_in[0];
    const float* enc_att_w  = (const float*)d_in[2];
    const float* enc_att_b  = (const float*)d_in[3];
    const float* dec_att_w  = (const float*)d_in[4];
    const float* dec_att_b  = (const float*)d_in[5];
    const float* full_att_w = (const float*)d_in[6];
    const float* full_att_b = (const float*)d_in[7];
    const float* ctx_w      = (const float*)d_in[8];
    const float* ctx_b      = (const float*)d_in[9];
    const float* W_ih       = (const float*)d_in[10];
    const float* b_ih       = (const float*)d_in[11];
    const float* W_hh       = (const float*)d_in[12];
    const float* b_hh       = (const float*)d_in[13];
    const float* topic_hid_w = (const float*)d_in[14];
    const float* topic_hid_b = (const float*)d_in[15];
    const float* topic_ctx_w = (const float*)d_in[16];
    const float* topic_ctx_b = (const float*)d_in[17];
    const float* stop_prev_w = (const float*)d_in[18];
    const float* stop_prev_b = (const float*)d_in[19];
    const float* stop_cur_w  = (const float*)d_in[20];
    const float* stop_cur_b  = (const float*)d_in[21];
    const float* final_stop_w = (const float*)d_in[22];
    const float* final_stop_b = (const float*)d_in[23];

    float* out_topics = (float*)d_out;                        // [B, ST, WI]
    float* out_ps     = (float*)d_out + (size_t)BB * ST * WI; // [B, ST, 2]

    char* ws = (char*)d_ws;
    size_t off = 0;
    auto alloc = [&](size_t bytes) -> void* {
        void* p = (void*)(ws + off);
        off += (bytes + 255) & ~(size_t)255;
        return p;
    };
    ushort* vis_att = (ushort*)alloc((size_t)BB * NR * AT * 2);      // 25.7 MB
    // split pool: enc(256)+hh(4096)+th(1024)+sp(256)+sc(256)+dec(256)
    //             +W_ih(4096)+topic_ctx(1024) rows
    const size_t WTOT = (size_t)11264 * 1024;
    ushort* wh = (ushort*)alloc(WTOT * 2);                           // 23.1 MB
    ushort* wl = (ushort*)alloc(WTOT * 2);                           // 23.1 MB
    ushort* hh_h   = (ushort*)alloc((size_t)(ST + 1) * BB * HH * 2); // 5.8 MB
    ushort* hh_l   = (ushort*)alloc((size_t)(ST + 1) * BB * HH * 2); // 5.8 MB
    ushort* att_all_h = (ushort*)alloc((size_t)ST * BB * DV * 2);    // 5.25 MB
    ushort* att_all_l = (ushort*)alloc((size_t)ST * BB * DV * 2);    // 5.25 MB
    float* cbuf    = (float*)alloc((size_t)BB * HH * 4);
    float* pt_all  = (float*)alloc((size_t)ST * BB * IS * 4);        // 2.6 MB
    // ctx-fold pools
    ushort* ctT_h  = (ushort*)alloc((size_t)SI * DV * 2);            // 2 MB
    ushort* ctT_l  = (ushort*)alloc((size_t)SI * DV * 2);
    ushort* cmb_h  = (ushort*)alloc((size_t)4 * HH * SI * 2);        // 8.4 MB
    ushort* cmb_l  = (ushort*)alloc((size_t)4 * HH * SI * 2);
    ushort* tcc_h  = (ushort*)alloc((size_t)WI * SI * 2);            // 2 MB
    ushort* tcc_l  = (ushort*)alloc((size_t)WI * SI * 2);
    float* bf_ih   = (float*)alloc((size_t)4 * HH * 4);
    float* bf_tc   = (float*)alloc((size_t)WI * 4);
    if (off > ws_size) return;  // core workspace too small — fail visibly
    // bf16 copy of vis (98 MB); fallback to fp32-A path if no room
    ushort* vis_bf = nullptr;
    {
        const size_t need = (size_t)BB * NR * DV * 2;
        if (off + need <= ws_size) vis_bf = (ushort*)alloc(need);
    }

    // weight segment offsets (elements) within the pool
    const size_t O_ENC = 0;              // 256x1024
    const size_t O_HH  = 262144;         // 4096x1024 (row-interleaved)
    const size_t O_TH  = 4456448;        // 1024x1024
    const size_t O_SP  = 5505024;        // 256x1024
    const size_t O_SC  = 5767168;        // 256x1024
    const size_t O_DEC = 6029312;        // 256x1024 (hi used by att_step)
    const size_t O_IH2 = 6291456;        // 4096x1024 (plain, ws A)
    const size_t O_TC2 = 10485760;       // 1024x1024 (plain, ws A)

    CvtTab tab;
    const float* srcs[8] = {enc_att_w, W_hh, topic_hid_w, stop_prev_w, stop_cur_w,
                            dec_att_w, W_ih, topic_ctx_w};
    const size_t offs[8] = {O_ENC, O_HH, O_TH, O_SP, O_SC, O_DEC, O_IH2, O_TC2};
    for (int i = 0; i < 8; ++i) {
        tab.s[i] = srcs[i];
        tab.h[i] = wh + offs[i];
        tab.l[i] = wl + offs[i];
    }

    hipMemsetAsync(hh_h, 0, (size_t)BB * HH * 2, stream);    // h_0 hi = 0
    hipMemsetAsync(hh_l, 0, (size_t)BB * HH * 2, stream);    // h_0 lo = 0
    hipMemsetAsync(cbuf, 0, (size_t)BB * HH * 4, stream);    // c_0 = 0

    convert_split<<<11264, 256, 0, stream>>>(tab);

    // ---- ctx-fold precompute (pre-split A; both ws GEMMs in ONE dispatch) ----
    transpose_split<<<dim3(SI / 32, DV / 32), 256, 0, stream>>>(ctx_w, ctT_h, ctT_l);
    mgemm_wsp2<<<1280, 256, 0, stream>>>(
        wh + O_IH2, wl + O_IH2, cmb_h, cmb_l,
        wh + O_TC2, wl + O_TC2, tcc_h, tcc_l,
        ctT_h, ctT_l);
    foldbias2<<<1280, 256, 0, stream>>>(W_ih, topic_ctx_w, ctx_b,
                                        b_ih, topic_ctx_b, bf_ih, bf_tc);

    // hoisted encoder projection (split conversion + GEMM — measured best)
    convert_vis<<<(BB * NR * DV) / (256 * 8), 256, 0, stream>>>(vis, vis_bf);
    mgemm_preb<<<(BB * NR) / 128, 512, 0, stream>>>(
        vis_bf, wh + O_ENC, wl + O_ENC, enc_att_b, vis_att);

    for (int s = 0; s < ST; ++s) {
        ushort* hch = hh_h + (size_t)s * BB * HH;
        ushort* hcl = hh_l + (size_t)s * BB * HH;
        ushort* hnh = hh_h + (size_t)(s + 1) * BB * HH;
        ushort* hnl = hh_l + (size_t)(s + 1) * BB * HH;
        ushort* ath = att_all_h + (size_t)s * BB * DV;
        ushort* atl = att_all_l + (size_t)s * BB * DV;
        // fused dec(bf16 w, h from hi+lo) + logits + softmax + apply
        att_step<1><<<BB, 1024, 0, stream>>>(vis_att, hch, hcl, wh + O_DEC, dec_att_b,
                                             full_att_w, full_att_b, vis_bf,
                                             ath, atl);
        // gates = att @ W_comb^T + bf_ih + h @ W_hh^T + b_hh, fused LSTM
        mgemm8_lstm<<<dim3(4 * HH / 32, BB / 64), 512, 0, stream>>>(
            ath, atl, cmb_h, cmb_l, bf_ih,
            hch, hcl, wh + O_HH, wl + O_HH, b_hh,
            SI, cbuf, hnh, hnl);
    }

    // deferred heads: topic (640 blocks) + stop (160 blocks) in ONE dispatch
    mgemm_heads<<<800, 256, 0, stream>>>(
        hh_h + (size_t)BB * HH, hh_l + (size_t)BB * HH,
        wh + O_TH, wl + O_TH, topic_hid_b,
        att_all_h, att_all_l, tcc_h, tcc_l, bf_tc,
        out_topics,
        hh_h, hh_l, wh + O_SP, wl + O_SP, stop_prev_b,
        hh_h + (size_t)BB * HH, hh_l + (size_t)BB * HH,
        wh + O_SC, wl + O_SC, stop_cur_b,
        pt_all);
    stop_final_all<<<ST * BB, 256, 0, stream>>>(pt_all, final_stop_w, final_stop_b, out_ps);
}

// Round 25
// 955.045 us; speedup vs baseline: 1.0443x; 1.0005x over previous
//
#include <hip/hip_runtime.h>
#include <hip/hip_bf16.h>
#include <math.h>

// Problem constants (SentenceLSTM)
static constexpr int BB = 256;    // batch
static constexpr int NR = 196;    // regions
static constexpr int DV = 1024;   // vis embed dim
static constexpr int HH = 1024;   // hidden
static constexpr int AT = 256;    // att dim
static constexpr int SI = 1024;   // sem input dim (ctx)
static constexpr int WI = 1024;   // topic width
static constexpr int IS = 256;    // stop inner dim
static constexpr int ST = 10;     // sentence steps

__device__ __forceinline__ float sigmoidf_(float x) { return 1.0f / (1.0f + expf(-x)); }

// bf16 round-to-nearest-even, bit-level
__device__ __forceinline__ ushort f2bf(float x) {
    uint u = __float_as_uint(x);
    return (ushort)((u + 0x7FFFu + ((u >> 16) & 1u)) >> 16);
}
__device__ __forceinline__ float bf2f(ushort b) { return __uint_as_float(((uint)b) << 16); }

using bf16x8 = __attribute__((ext_vector_type(8))) short;
using f32x4  = __attribute__((ext_vector_type(4))) float;
#define MFMA_B16(a, b, c) __builtin_amdgcn_mfma_f32_16x16x32_bf16((a), (b), (c), 0, 0, 0)

struct CvtTab { const float* s[8]; ushort* h[8]; ushort* l[8]; };

// ---------------------------------------------------------------------------
// setup_all: MERGED independent setup streaming work, one dispatch.
//   blocks [0, 11264):        convert_split (8 weight segments; seg5 hi-only)
//   blocks [11264, 12288):    transpose_split of ctx_w -> ctT hi/lo
//   blocks [12288, 13568):    foldbias2 (bf_ih, bf_tc)
//   blocks [13568, 38656):    convert_vis (vis fp32 -> bf16)
// All four read only kernel inputs and write disjoint ws regions.
// ---------------------------------------------------------------------------
__global__ __launch_bounds__(256) void setup_all(
    CvtTab tab,
    const float* __restrict__ ctxw, ushort* __restrict__ ctT_h, ushort* __restrict__ ctT_l,
    const float* __restrict__ Wih, const float* __restrict__ Wtc,
    const float* __restrict__ cb,
    const float* __restrict__ bih, const float* __restrict__ btc,
    float* __restrict__ out_ih, float* __restrict__ out_tc,
    const float* __restrict__ vis_src, ushort* __restrict__ vis_dst)
{
    __shared__ float T[32][33];   // used by transpose segment only
    const int bid = blockIdx.x;

    if (bid < 11264) {
        // ---- convert_split ----
        const int cum[9] = {0, 256, 4352, 5376, 5632, 5888, 6144, 10240, 11264};
        int seg = 0;
#pragma unroll
        for (int i = 1; i < 8; ++i) if (bid >= cum[i]) seg = i;
        const float* s = tab.s[seg];
        ushort* h = tab.h[seg];
        ushort* l = tab.l[seg];
        const int r = bid - cum[seg];
        int rd = r;
        if (seg == 1) rd = (r & 1023) * 4 + (r >> 10);
        const int src = r * 1024 + threadIdx.x * 4;
        const size_t dst = (size_t)rd * 1024 + threadIdx.x * 4;
        float4 v = *(const float4*)(s + src);
        ushort h0 = f2bf(v.x), h1 = f2bf(v.y), h2 = f2bf(v.z), h3 = f2bf(v.w);
        uint2 hq;
        hq.x = h0 | ((uint)h1 << 16); hq.y = h2 | ((uint)h3 << 16);
        *(uint2*)(h + dst) = hq;
        if (seg != 5) {   // dec_att lo is dead — skip its math and store
            uint2 lq;
            ushort l0 = f2bf(v.x - bf2f(h0)), l1 = f2bf(v.y - bf2f(h1));
            ushort l2 = f2bf(v.z - bf2f(h2)), l3 = f2bf(v.w - bf2f(h3));
            lq.x = l0 | ((uint)l1 << 16); lq.y = l2 | ((uint)l3 << 16);
            *(uint2*)(l + dst) = lq;
        }
    } else if (bid < 12288) {
        // ---- transpose_split: ctT = split(ctx_w^T) ----
        const int lb = bid - 11264;
        const int tx = threadIdx.x & 31, ty = threadIdx.x >> 5;
        const int k0 = (lb & 31) * 32, n0 = (lb >> 5) * 32;
#pragma unroll
        for (int j = 0; j < 4; ++j)
            T[ty + 8 * j][tx] = ctxw[(size_t)(k0 + ty + 8 * j) * 1024 + n0 + tx];
        __syncthreads();
#pragma unroll
        for (int j = 0; j < 4; ++j) {
            const float v = T[tx][ty + 8 * j];
            const ushort h = f2bf(v);
            const size_t o = (size_t)(n0 + ty + 8 * j) * 1024 + k0 + tx;
            ctT_h[o] = h;
            ctT_l[o] = f2bf(v - bf2f(h));
        }
    } else if (bid < 13568) {
        // ---- foldbias2 ----
        const int lb = bid - 12288;
        const int lane = threadIdx.x & 63;
        const float* W; const float* b; float* out; int n;
        if (lb < 1024) { W = Wih; b = bih; out = out_ih; n = lb * 4 + (threadIdx.x >> 6); }
        else { W = Wtc; b = btc; out = out_tc; n = (lb - 1024) * 4 + (threadIdx.x >> 6); }
        const float* wr = W + (size_t)n * 1024;
        float p = 0.f;
#pragma unroll
        for (int i = 0; i < 4; ++i) {
            const float4 wv = *(const float4*)&wr[i * 256 + lane * 4];
            const float4 vv = *(const float4*)&cb[i * 256 + lane * 4];
            p = fmaf(wv.x, vv.x, p); p = fmaf(wv.y, vv.y, p);
            p = fmaf(wv.z, vv.z, p); p = fmaf(wv.w, vv.w, p);
        }
        for (int off = 32; off; off >>= 1) p += __shfl_down(p, off);
        if (lane == 0) out[n] = p + b[n];
    } else {
        // ---- convert_vis ----
        const int lb = bid - 13568;
        const size_t i = ((size_t)lb * 256 + threadIdx.x) * 8;
        const float4 v0 = *(const float4*)(vis_src + i);
        const float4 v1 = *(const float4*)(vis_src + i + 4);
        uint4 o;
        o.x = f2bf(v0.x) | ((uint)f2bf(v0.y) << 16);
        o.y = f2bf(v0.z) | ((uint)f2bf(v0.w) << 16);
        o.z = f2bf(v1.x) | ((uint)f2bf(v1.y) << 16);
        o.w = f2bf(v1.z) | ((uint)f2bf(v1.w) << 16);
        *(uint4*)(vis_dst + i) = o;
    }
}

// ---------------------------------------------------------------------------
// mgemm_wsp2: MERGED weight synthesis, pre-split A, shared B = ctx_w^T.
// 1280 blocks: bid < 1024 -> A=W_ih (4096x1024), C=cmb, ILV row remap;
//              bid >= 1024 -> A=topic_ctx_w (1024x1024), C=tcc, plain rows.
// Csplit = A @ W^T, N=SI, K=DV for both.
// ---------------------------------------------------------------------------
__global__ __launch_bounds__(256) void mgemm_wsp2(
    const ushort* __restrict__ A1h, const ushort* __restrict__ A1l,
    ushort* __restrict__ C1h, ushort* __restrict__ C1l,
    const ushort* __restrict__ A2h, const ushort* __restrict__ A2l,
    ushort* __restrict__ C2h, ushort* __restrict__ C2l,
    const ushort* __restrict__ Wh, const ushort* __restrict__ Wl)
{
    __shared__ __align__(16) ushort SM[4 * 64 * 40];
    ushort* Ah = SM; ushort* Al = SM + 2560; ushort* Bh = SM + 5120; ushort* Bl = SM + 7680;

    const int bid = blockIdx.x;
    const int seg1 = (bid < 1024) ? 1 : 0;
    const int lb = seg1 ? bid : (bid - 1024);
    const int bx = lb & 15, by = lb >> 4;
    const int m0 = by * 64, n0 = bx * 64;
    const ushort* Ahg = seg1 ? A1h : A2h;
    const ushort* Alg = seg1 ? A1l : A2l;
    ushort* Ch = seg1 ? C1h : C2h;
    ushort* Cl = seg1 ? C1l : C2l;
    const int N = SI, K = DV;

    const int t = threadIdx.x;
    const int w = t >> 6, lane = t & 63;
    const int l15 = lane & 15, q = lane >> 4;
    const int sr = t >> 2, sq = (t & 3) * 8;
    const int nch = K >> 5;

    f32x4 acc[4] = {};
    uint4 pah, pal, pbh, pbl;
    auto pref = [&](int c) {
        const int k0 = c << 5;
        const size_t ab = (size_t)(m0 + sr) * K + k0 + sq;
        pah = *(const uint4*)&Ahg[ab];
        pal = *(const uint4*)&Alg[ab];
        pbh = *(const uint4*)&Wh[(size_t)(n0 + sr) * K + k0 + sq];
        pbl = *(const uint4*)&Wl[(size_t)(n0 + sr) * K + k0 + sq];
    };
    pref(0);

    for (int c = 0; c < nch; ++c) {
        __syncthreads();
        *(uint4*)&Ah[sr * 40 + sq] = pah;
        *(uint4*)&Al[sr * 40 + sq] = pal;
        *(uint4*)&Bh[sr * 40 + sq] = pbh;
        *(uint4*)&Bl[sr * 40 + sq] = pbl;
        __syncthreads();
        if (c + 1 < nch) pref(c + 1);
        const bf16x8 bh = *(const bf16x8*)&Bh[(w * 16 + l15) * 40 + q * 8];
        const bf16x8 bl = *(const bf16x8*)&Bl[(w * 16 + l15) * 40 + q * 8];
#pragma unroll
        for (int mi = 0; mi < 4; ++mi) {
            const bf16x8 ah = *(const bf16x8*)&Ah[(mi * 16 + l15) * 40 + q * 8];
            const bf16x8 al = *(const bf16x8*)&Al[(mi * 16 + l15) * 40 + q * 8];
            acc[mi] = MFMA_B16(ah, bh, acc[mi]);
            acc[mi] = MFMA_B16(ah, bl, acc[mi]);
            acc[mi] = MFMA_B16(al, bh, acc[mi]);
        }
    }

    const int col = n0 + w * 16 + l15;
#pragma unroll
    for (int mi = 0; mi < 4; ++mi) {
#pragma unroll
        for (int j = 0; j < 4; ++j) {
            const int row = m0 + mi * 16 + q * 4 + j;
            const int ro = seg1 ? ((row & 1023) * 4 + (row >> 10)) : row;
            const float v = acc[mi][j];
            const ushort h = f2bf(v);
            Ch[(size_t)ro * N + col] = h;
            Cl[(size_t)ro * N + col] = f2bf(v - bf2f(h));
        }
    }
}

// ---------------------------------------------------------------------------
// mgemm_heads: MERGED deferred-head GEMM. 800 blocks, 1D:
//   bid <  640: topic tile (bx=bid&15, by=bid>>4), OMAP row remap, ldc=WI
//   bid >= 640: stop  tile (bx=(bid-640)&3, by=(bid-640)>>2), ldc=IS
// Both: C = tanh(A1*W1^T + A2*W2^T + b1+b2), K=1024, pre-split operands.
// ---------------------------------------------------------------------------
__global__ __launch_bounds__(256) void mgemm_heads(
    const ushort* __restrict__ tA1h, const ushort* __restrict__ tA1l,
    const ushort* __restrict__ tW1h, const ushort* __restrict__ tW1l,
    const float* __restrict__ tb1,
    const ushort* __restrict__ tA2h, const ushort* __restrict__ tA2l,
    const ushort* __restrict__ tW2h, const ushort* __restrict__ tW2l,
    const float* __restrict__ tb2,
    float* __restrict__ tC,
    const ushort* __restrict__ sA1h, const ushort* __restrict__ sA1l,
    const ushort* __restrict__ sW1h, const ushort* __restrict__ sW1l,
    const float* __restrict__ sb1,
    const ushort* __restrict__ sA2h, const ushort* __restrict__ sA2l,
    const ushort* __restrict__ sW2h, const ushort* __restrict__ sW2l,
    const float* __restrict__ sb2,
    float* __restrict__ sC)
{
    __shared__ __align__(16) ushort SM[4 * 64 * 40];
    ushort* Ah = SM; ushort* Al = SM + 2560; ushort* Bh = SM + 5120; ushort* Bl = SM + 7680;

    const int bid = blockIdx.x;
    const int topic = (bid < 640) ? 1 : 0;
    const int lb = topic ? bid : (bid - 640);
    const int bx = topic ? (lb & 15) : (lb & 3);
    const int by = topic ? (lb >> 4) : (lb >> 2);
    const int m0 = by * 64, n0 = bx * 64;
    const int ldc = topic ? WI : IS;

    const ushort* A1h = topic ? tA1h : sA1h;  const ushort* A1l = topic ? tA1l : sA1l;
    const ushort* W1h = topic ? tW1h : sW1h;  const ushort* W1l = topic ? tW1l : sW1l;
    const float*  b1  = topic ? tb1  : sb1;
    const ushort* A2h = topic ? tA2h : sA2h;  const ushort* A2l = topic ? tA2l : sA2l;
    const ushort* W2h = topic ? tW2h : sW2h;  const ushort* W2l = topic ? tW2l : sW2l;
    const float*  b2  = topic ? tb2  : sb2;
    float* C = topic ? tC : sC;

    const int t = threadIdx.x;
    const int w = t >> 6, lane = t & 63;
    const int l15 = lane & 15, q = lane >> 4;
    const int sr = t >> 2, sq = (t & 3) * 8;
    const int K = HH;
    const int KC = K >> 5, nch = 2 * KC;

    f32x4 acc[4] = {};
    uint4 pah, pal, pbh, pbl;

    auto pref = [&](int c) {
        const int pass = (c >= KC) ? 1 : 0;
        const int k0 = (c - pass * KC) << 5;
        const ushort* Axh = pass ? A2h : A1h;
        const ushort* Axl = pass ? A2l : A1l;
        const ushort* Wh = pass ? W2h : W1h;
        const ushort* Wl = pass ? W2l : W1l;
        const size_t ab = (size_t)(m0 + sr) * K + k0 + sq;
        pah = *(const uint4*)&Axh[ab];
        pal = *(const uint4*)&Axl[ab];
        pbh = *(const uint4*)&Wh[(size_t)(n0 + sr) * K + k0 + sq];
        pbl = *(const uint4*)&Wl[(size_t)(n0 + sr) * K + k0 + sq];
    };
    pref(0);

    for (int c = 0; c < nch; ++c) {
        __syncthreads();
        *(uint4*)&Ah[sr * 40 + sq] = pah;
        *(uint4*)&Al[sr * 40 + sq] = pal;
        *(uint4*)&Bh[sr * 40 + sq] = pbh;
        *(uint4*)&Bl[sr * 40 + sq] = pbl;
        __syncthreads();
        if (c + 1 < nch) pref(c + 1);
        const bf16x8 bh = *(const bf16x8*)&Bh[(w * 16 + l15) * 40 + q * 8];
        const bf16x8 bl = *(const bf16x8*)&Bl[(w * 16 + l15) * 40 + q * 8];
#pragma unroll
        for (int mi = 0; mi < 4; ++mi) {
            const bf16x8 ah = *(const bf16x8*)&Ah[(mi * 16 + l15) * 40 + q * 8];
            const bf16x8 al = *(const bf16x8*)&Al[(mi * 16 + l15) * 40 + q * 8];
            acc[mi] = MFMA_B16(ah, bh, acc[mi]);
            acc[mi] = MFMA_B16(ah, bl, acc[mi]);
            acc[mi] = MFMA_B16(al, bh, acc[mi]);
        }
    }

    const int col = n0 + w * 16 + l15;
    const float bias = b1[col] + b2[col];
#pragma unroll
    for (int mi = 0; mi < 4; ++mi) {
#pragma unroll
        for (int j = 0; j < 4; ++j) {
            const int row = m0 + mi * 16 + q * 4 + j;
            const float v = tanhf(acc[mi][j] + bias);
            if (topic)
                C[((size_t)(row & 255) * ST + (row >> 8)) * ldc + col] = v;
            else
                C[(size_t)row * ldc + col] = v;
        }
    }
}

// ---------------------------------------------------------------------------
// mgemm8_lstm: BK=64 body, pre-split activations; B-staging stride 64 with
// XOR swizzle; comb/G aliased into group-1 staging. LDS 53248 B.
// h state kept ONLY as hi/lo bf16 (no fp32 h write).
// ---------------------------------------------------------------------------
__global__ __launch_bounds__(512, 6) void mgemm8_lstm(
    const ushort* __restrict__ A1h, const ushort* __restrict__ A1l,
    const ushort* __restrict__ W1h, const ushort* __restrict__ W1l,
    const float* __restrict__ b1,
    const ushort* __restrict__ A2h, const ushort* __restrict__ A2l,
    const ushort* __restrict__ W2h, const ushort* __restrict__ W2l,
    const float* __restrict__ b2,
    int K, float* __restrict__ cvec,
    ushort* __restrict__ hnh, ushort* __restrict__ hnl)
{
    __shared__ __align__(16) ushort SM[26624];   // 53248 B

    const int t = threadIdx.x;
    const int m0 = blockIdx.y * 64, n0 = blockIdx.x * 32;
    const int w = t >> 6, lane = t & 63;
    const int g = w >> 2, wg = w & 3;
    const int l15 = lane & 15, q = lane >> 4;
    const int tl = t & 255;
    const int sr = tl >> 2, sq4 = (tl & 3) * 16;
    const int br = tl >> 3, bq = (tl & 7) * 8;
    const int mh = wg >> 1;
    const int colL = (wg & 1) * 16 + l15;

    ushort* Ah = SM + g * 13312;
    ushort* Al = Ah + 4608;
    ushort* Bh = Al + 4608;
    ushort* Bl = Bh + 2048;

    const int nchg = K >> 6;
    const ushort* Ahg = g ? A2h : A1h;
    const ushort* Alg = g ? A2l : A1l;
    const ushort* Wh  = g ? W2h : W1h;
    const ushort* Wl  = g ? W2l : W1l;

    const int bwi = br * 64 + (bq ^ ((br & 7) << 3));

    f32x4 acc[2] = {};
    uint4 pah0, pah1, pal0, pal1, pbh, pbl;
    auto pref = [&](int c) {
        const int k0 = c << 6;
        const size_t ab = (size_t)(m0 + sr) * K + k0 + sq4;
        pah0 = *(const uint4*)&Ahg[ab];
        pah1 = *(const uint4*)&Ahg[ab + 8];
        pal0 = *(const uint4*)&Alg[ab];
        pal1 = *(const uint4*)&Alg[ab + 8];
        pbh = *(const uint4*)&Wh[(size_t)(n0 + br) * K + k0 + bq];
        pbl = *(const uint4*)&Wl[(size_t)(n0 + br) * K + k0 + bq];
    };
    pref(0);

    for (int c = 0; c < nchg; ++c) {
        __syncthreads();
        *(uint4*)&Ah[sr * 72 + sq4]     = pah0;
        *(uint4*)&Ah[sr * 72 + sq4 + 8] = pah1;
        *(uint4*)&Al[sr * 72 + sq4]     = pal0;
        *(uint4*)&Al[sr * 72 + sq4 + 8] = pal1;
        *(uint4*)&Bh[bwi] = pbh;
        *(uint4*)&Bl[bwi] = pbl;
        __syncthreads();
        if (c + 1 < nchg) pref(c + 1);
#pragma unroll
        for (int ks = 0; ks < 2; ++ks) {
            const int bro = colL * 64 + ((ks * 32 + q * 8) ^ ((colL & 7) << 3));
            const bf16x8 bh = *(const bf16x8*)&Bh[bro];
            const bf16x8 bl = *(const bf16x8*)&Bl[bro];
#pragma unroll
            for (int i = 0; i < 2; ++i) {
                const int mi = mh * 2 + i;
                const bf16x8 ah = *(const bf16x8*)&Ah[(mi * 16 + l15) * 72 + ks * 32 + q * 8];
                const bf16x8 al = *(const bf16x8*)&Al[(mi * 16 + l15) * 72 + ks * 32 + q * 8];
                acc[i] = MFMA_B16(ah, bh, acc[i]);
                acc[i] = MFMA_B16(ah, bl, acc[i]);
                acc[i] = MFMA_B16(al, bh, acc[i]);
            }
        }
    }

    // combine group-1 partials into group-0
    float* comb = (float*)(SM + 13312);
    __syncthreads();
    if (g == 1) {
#pragma unroll
        for (int i = 0; i < 2; ++i)
#pragma unroll
            for (int j = 0; j < 4; ++j) comb[tl * 9 + i * 4 + j] = acc[i][j];
    }
    __syncthreads();
    if (g == 0) {
#pragma unroll
        for (int i = 0; i < 2; ++i)
#pragma unroll
            for (int j = 0; j < 4; ++j) acc[i][j] += comb[tl * 9 + i * 4 + j];
    }

    // LSTM pointwise. Gate cols interleaved (col' = unit*4+gate).
    float* G = (float*)(SM + 17920);
    if (g == 0) {
        const int colG = n0 + colL;
        const int gate = colG & 3, unit = colG >> 2;
        const float bias = b1[gate * 1024 + unit] + b2[gate * 1024 + unit];
#pragma unroll
        for (int i = 0; i < 2; ++i) {
            const int mi = mh * 2 + i;
#pragma unroll
            for (int j = 0; j < 4; ++j)
                G[(mi * 16 + q * 4 + j) * 40 + colL] = acc[i][j] + bias;
        }
    }
    __syncthreads();
    {
        const int row = t >> 3, ul = t & 7;
        const float4 g4 = *(const float4*)&G[row * 40 + ul * 4];  // i,f,g,o
        const size_t ci = (size_t)(m0 + row) * HH + (n0 >> 2) + ul;
        const float cn = sigmoidf_(g4.y) * cvec[ci] + sigmoidf_(g4.x) * tanhf(g4.z);
        cvec[ci] = cn;
        const float hv = sigmoidf_(g4.w) * tanhf(cn);
        const ushort hhi = f2bf(hv);
        hnh[ci] = hhi;
        hnl[ci] = f2bf(hv - bf2f(hhi));
    }
}

// ---------------------------------------------------------------------------
// mgemm_preb: vis_att(bf16) = vh(bf16) @ enc^T + b, 2-term (A-hi only,
// B hi+lo). Tile 128M x 256N, 512 threads, BK=32, reg prefetch after barrier.
// ---------------------------------------------------------------------------
__global__ __launch_bounds__(512) void mgemm_preb(
    const ushort* __restrict__ vh, const ushort* __restrict__ Wh, const ushort* __restrict__ Wl,
    const float* __restrict__ bias, ushort* __restrict__ C)
{
    __shared__ __align__(16) ushort Avh[128 * 40];
    __shared__ __align__(16) ushort Bh[256 * 40];
    __shared__ __align__(16) ushort Bl[256 * 40];

    const int t = threadIdx.x;
    const int m0 = blockIdx.x * 128;
    const int w = t >> 6, lane = t & 63;
    const int rg = w >> 2, cg = w & 3;
    const int l15 = lane & 15, q = lane >> 4;
    const int ar = t >> 2, ac = (t & 3) * 8;
    const int brr = t >> 1, bc = (t & 1) * 16;
    const int K = DV;

    f32x4 acc[4][4] = {};
    uint4 pa, pbh0, pbh1, pbl0, pbl1;
    auto pref = [&](int c) {
        const int k0 = c << 5;
        pa   = *(const uint4*)&vh[(size_t)(m0 + ar) * K + k0 + ac];
        const size_t bb = (size_t)brr * K + k0 + bc;
        pbh0 = *(const uint4*)&Wh[bb];
        pbh1 = *(const uint4*)&Wh[bb + 8];
        pbl0 = *(const uint4*)&Wl[bb];
        pbl1 = *(const uint4*)&Wl[bb + 8];
    };
    pref(0);

    for (int c = 0; c < 32; ++c) {
        __syncthreads();
        *(uint4*)&Avh[ar * 40 + ac] = pa;
        *(uint4*)&Bh[brr * 40 + bc]     = pbh0;
        *(uint4*)&Bh[brr * 40 + bc + 8] = pbh1;
        *(uint4*)&Bl[brr * 40 + bc]     = pbl0;
        *(uint4*)&Bl[brr * 40 + bc + 8] = pbl1;
        __syncthreads();
        if (c + 1 < 32) pref(c + 1);

        bf16x8 ah[4];
#pragma unroll
        for (int mi = 0; mi < 4; ++mi)
            ah[mi] = *(const bf16x8*)&Avh[(rg * 64 + mi * 16 + l15) * 40 + q * 8];
#pragma unroll
        for (int ni = 0; ni < 4; ++ni) {
            const bf16x8 bh = *(const bf16x8*)&Bh[(cg * 64 + ni * 16 + l15) * 40 + q * 8];
            const bf16x8 bl = *(const bf16x8*)&Bl[(cg * 64 + ni * 16 + l15) * 40 + q * 8];
#pragma unroll
            for (int mi = 0; mi < 4; ++mi) {
                acc[mi][ni] = MFMA_B16(ah[mi], bh, acc[mi][ni]);
                acc[mi][ni] = MFMA_B16(ah[mi], bl, acc[mi][ni]);
            }
        }
    }

#pragma unroll
    for (int ni = 0; ni < 4; ++ni) {
        const int col = cg * 64 + ni * 16 + l15;
        const float bb = bias[col];
#pragma unroll
        for (int mi = 0; mi < 4; ++mi)
#pragma unroll
            for (int j = 0; j < 4; ++j) {
                const int row = m0 + rg * 64 + mi * 16 + q * 4 + j;
                C[(size_t)row * AT + col] = f2bf(acc[mi][ni][j] + bb);
            }
    }
}

// ---------------------------------------------------------------------------
// att_step: per batch row b (one 1024-thread block): dec(bf16 weights,
// h reconstructed from hi/lo) + logits + softmax + apply. Emits hi/lo att.
// ---------------------------------------------------------------------------
template <int VBF>
__global__ __launch_bounds__(1024) void att_step(
    const ushort* __restrict__ vis_att,
    const ushort* __restrict__ hch, const ushort* __restrict__ hcl,
    const ushort* __restrict__ dec_wh, const float* __restrict__ dec_b,
    const float* __restrict__ fw, const float* __restrict__ fbp,
    const void* __restrict__ visp,
    ushort* __restrict__ att_h, ushort* __restrict__ att_l)
{
    const int b = blockIdx.x;
    const int t = threadIdx.x;
    const int lane = t & 63;
    const int w = t >> 6;

    __shared__ float hs[HH];
    __shared__ float decs[AT];
    __shared__ float fwv[AT];
    __shared__ float logit[NR + 4];
    __shared__ float sc[NR + 4];
    __shared__ float red[8];
    __shared__ float part[8][DV];

    hs[t] = bf2f(hch[(size_t)b * HH + t]) + bf2f(hcl[(size_t)b * HH + t]);
    if (t < AT) fwv[t] = fw[t];
    __syncthreads();
    const float fb = fbp[0];

    // phase 0: dec — bf16(hi) weights, 16B loads. Wave w owns a = w*16..+15.
#pragma unroll
    for (int j = 0; j < 16; ++j) {
        const int a = w * 16 + j;
        const ushort* wr = dec_wh + (size_t)a * HH;
        float p = 0.f;
#pragma unroll
        for (int i = 0; i < 2; ++i) {
            const uint4 wv = *(const uint4*)&wr[i * 512 + lane * 8];
            const float4 hv0 = *(const float4*)&hs[i * 512 + lane * 8];
            const float4 hv1 = *(const float4*)&hs[i * 512 + lane * 8 + 4];
            p = fmaf(bf2f((ushort)(wv.x & 0xFFFF)), hv0.x, p);
            p = fmaf(bf2f((ushort)(wv.x >> 16)),    hv0.y, p);
            p = fmaf(bf2f((ushort)(wv.y & 0xFFFF)), hv0.z, p);
            p = fmaf(bf2f((ushort)(wv.y >> 16)),    hv0.w, p);
            p = fmaf(bf2f((ushort)(wv.z & 0xFFFF)), hv1.x, p);
            p = fmaf(bf2f((ushort)(wv.z >> 16)),    hv1.y, p);
            p = fmaf(bf2f((ushort)(wv.w & 0xFFFF)), hv1.z, p);
            p = fmaf(bf2f((ushort)(wv.w >> 16)),    hv1.w, p);
        }
        for (int off = 32; off; off >>= 1) p += __shfl_down(p, off);
        if (lane == 0) decs[a] = p + dec_b[a];
    }
    __syncthreads();

    // phase 1: logits
    for (int n = w; n < NR; n += 16) {
        const ushort4 v4 = *(const ushort4*)&vis_att[((size_t)b * NR + n) * AT + lane * 4];
        const int a = lane * 4;
        float s = tanhf(bf2f(v4.x) + decs[a]) * fwv[a];
        s = fmaf(tanhf(bf2f(v4.y) + decs[a + 1]), fwv[a + 1], s);
        s = fmaf(tanhf(bf2f(v4.z) + decs[a + 2]), fwv[a + 2], s);
        s = fmaf(tanhf(bf2f(v4.w) + decs[a + 3]), fwv[a + 3], s);
        for (int off = 32; off; off >>= 1) s += __shfl_down(s, off);
        if (lane == 0) logit[n] = s + fb;
    }
    __syncthreads();

    // phase 2: softmax
    float m = -1e30f, e = 0.f;
    if (t < NR) m = logit[t];
    if (t < 256) {
        for (int off = 32; off; off >>= 1) m = fmaxf(m, __shfl_down(m, off));
        if (lane == 0) red[w] = m;
    }
    __syncthreads();
    m = fmaxf(fmaxf(red[0], red[1]), fmaxf(red[2], red[3]));
    if (t < NR) e = expf(logit[t] - m);
    if (t < 256) {
        float ss = e;
        for (int off = 32; off; off >>= 1) ss += __shfl_down(ss, off);
        if (lane == 0) red[4 + w] = ss;
    }
    __syncthreads();
    const float S = red[4] + red[5] + red[6] + red[7];
    if (t < NR) sc[t] = e / S;
    __syncthreads();

    // phase 3: apply — 8-way region split (25,25,25,25,24,24,24,24)
    const int slice = t >> 7;
    const int c8 = (t & 127) * 8;
    const int nbeg = (slice <= 4) ? 25 * slice : 100 + 24 * (slice - 4);
    const int nend = (slice < 4) ? nbeg + 25 : nbeg + 24;
    float a0 = 0.f, a1 = 0.f, a2 = 0.f, a3 = 0.f;
    float a4 = 0.f, a5 = 0.f, a6 = 0.f, a7 = 0.f;
    if (VBF) {
        const ushort* vb = (const ushort*)visp + (size_t)b * NR * DV + c8;
        for (int n = nbeg; n < nend; ++n) {
            const float s = sc[n];
            const uint4 v = *(const uint4*)&vb[(size_t)n * DV];
            a0 = fmaf(s, bf2f((ushort)(v.x & 0xFFFF)), a0);
            a1 = fmaf(s, bf2f((ushort)(v.x >> 16)), a1);
            a2 = fmaf(s, bf2f((ushort)(v.y & 0xFFFF)), a2);
            a3 = fmaf(s, bf2f((ushort)(v.y >> 16)), a3);
            a4 = fmaf(s, bf2f((ushort)(v.z & 0xFFFF)), a4);
            a5 = fmaf(s, bf2f((ushort)(v.z >> 16)), a5);
            a6 = fmaf(s, bf2f((ushort)(v.w & 0xFFFF)), a6);
            a7 = fmaf(s, bf2f((ushort)(v.w >> 16)), a7);
        }
    } else {
        const float* vb = (const float*)visp + (size_t)b * NR * DV + c8;
        for (int n = nbeg; n < nend; ++n) {
            const float s = sc[n];
            const float4 v0 = *(const float4*)&vb[(size_t)n * DV];
            const float4 v1 = *(const float4*)&vb[(size_t)n * DV + 4];
            a0 = fmaf(s, v0.x, a0); a1 = fmaf(s, v0.y, a1);
            a2 = fmaf(s, v0.z, a2); a3 = fmaf(s, v0.w, a3);
            a4 = fmaf(s, v1.x, a4); a5 = fmaf(s, v1.y, a5);
            a6 = fmaf(s, v1.z, a6); a7 = fmaf(s, v1.w, a7);
        }
    }
    float4 av0; av0.x = a0; av0.y = a1; av0.z = a2; av0.w = a3;
    float4 av1; av1.x = a4; av1.y = a5; av1.z = a6; av1.w = a7;
    *(float4*)&part[slice][c8]     = av0;
    *(float4*)&part[slice][c8 + 4] = av1;
    __syncthreads();
    const float v = ((part[0][t] + part[1][t]) + (part[2][t] + part[3][t]))
                  + ((part[4][t] + part[5][t]) + (part[6][t] + part[7][t]));
    const ushort vh16 = f2bf(v);
    att_h[(size_t)b * DV + t] = vh16;
    att_l[(size_t)b * DV + t] = f2bf(v - bf2f(vh16));
}

// ---------------------------------------------------------------------------
// batched final stop projection over all (s,b): row = s*BB + b.
// ---------------------------------------------------------------------------
__global__ __launch_bounds__(256) void stop_final_all(
    const float* __restrict__ pt, const float* __restrict__ fw,
    const float* __restrict__ fb, float* __restrict__ outp)
{
    const int row = blockIdx.x;
    const int s = row >> 8, b = row & 255;
    const int t = threadIdx.x;
    const int lane = t & 63;
    const int w = t >> 6;

    __shared__ float red[16];
    const float v = pt[(size_t)row * IS + t];
    float p0 = v * fw[t];
    float p1 = v * fw[IS + t];
    for (int off = 32; off; off >>= 1) {
        p0 += __shfl_down(p0, off);
        p1 += __shfl_down(p1, off);
    }
    if (lane == 0) { red[w] = p0; red[8 + w] = p1; }
    __syncthreads();
    if (t == 0) {
        outp[((size_t)b * ST + s) * 2 + 0] = red[0] + red[1] + red[2] + red[3] + fb[0];
        outp[((size_t)b * ST + s) * 2 + 1] = red[8] + red[9] + red[10] + red[11] + fb[1];
    }
}

// ---------------------------------------------------------------------------
extern "C" void kernel_launch(void* const* d_in, const int* in_sizes, int n_in,
                              void* d_out, int out_size, void* d_ws, size_t ws_size,
                              hipStream_t stream)
{
    const float* vis        = (const float*)d_in[0];
    const float* enc_att_w  = (const float*)d_in[2];
    const float* enc_att_b  = (const float*)d_in[3];
    const float* dec_att_w  = (const float*)d_in[4];
    const float* dec_att_b  = (const float*)d_in[5];
    const float* full_att_w = (const float*)d_in[6];
    const float* full_att_b = (const float*)d_in[7];
    const float* ctx_w      = (const float*)d_in[8];
    const float* ctx_b      = (const float*)d_in[9];
    const float* W_ih       = (const float*)d_in[10];
    const float* b_ih       = (const float*)d_in[11];
    const float* W_hh       = (const float*)d_in[12];
    const float* b_hh       = (const float*)d_in[13];
    const float* topic_hid_w = (const float*)d_in[14];
    const float* topic_hid_b = (const float*)d_in[15];
    const float* topic_ctx_w = (const float*)d_in[16];
    const float* topic_ctx_b = (const float*)d_in[17];
    const float* stop_prev_w = (const float*)d_in[18];
    const float* stop_prev_b = (const float*)d_in[19];
    const float* stop_cur_w  = (const float*)d_in[20];
    const float* stop_cur_b  = (const float*)d_in[21];
    const float* final_stop_w = (const float*)d_in[22];
    const float* final_stop_b = (const float*)d_in[23];

    float* out_topics = (float*)d_out;                        // [B, ST, WI]
    float* out_ps     = (float*)d_out + (size_t)BB * ST * WI; // [B, ST, 2]

    char* ws = (char*)d_ws;
    size_t off = 0;
    auto alloc = [&](size_t bytes) -> void* {
        void* p = (void*)(ws + off);
        off += (bytes + 255) & ~(size_t)255;
        return p;
    };
    ushort* vis_att = (ushort*)alloc((size_t)BB * NR * AT * 2);      // 25.7 MB
    // split pool: enc(256)+hh(4096)+th(1024)+sp(256)+sc(256)+dec(256)
    //             +W_ih(4096)+topic_ctx(1024) rows
    const size_t WTOT = (size_t)11264 * 1024;
    ushort* wh = (ushort*)alloc(WTOT * 2);                           // 23.1 MB
    ushort* wl = (ushort*)alloc(WTOT * 2);                           // 23.1 MB
    ushort* hh_h   = (ushort*)alloc((size_t)(ST + 1) * BB * HH * 2); // 5.8 MB
    ushort* hh_l   = (ushort*)alloc((size_t)(ST + 1) * BB * HH * 2); // 5.8 MB
    ushort* att_all_h = (ushort*)alloc((size_t)ST * BB * DV * 2);    // 5.25 MB
    ushort* att_all_l = (ushort*)alloc((size_t)ST * BB * DV * 2);    // 5.25 MB
    float* cbuf    = (float*)alloc((size_t)BB * HH * 4);
    float* pt_all  = (float*)alloc((size_t)ST * BB * IS * 4);        // 2.6 MB
    // ctx-fold pools
    ushort* ctT_h  = (ushort*)alloc((size_t)SI * DV * 2);            // 2 MB
    ushort* ctT_l  = (ushort*)alloc((size_t)SI * DV * 2);
    ushort* cmb_h  = (ushort*)alloc((size_t)4 * HH * SI * 2);        // 8.4 MB
    ushort* cmb_l  = (ushort*)alloc((size_t)4 * HH * SI * 2);
    ushort* tcc_h  = (ushort*)alloc((size_t)WI * SI * 2);            // 2 MB
    ushort* tcc_l  = (ushort*)alloc((size_t)WI * SI * 2);
    float* bf_ih   = (float*)alloc((size_t)4 * HH * 4);
    float* bf_tc   = (float*)alloc((size_t)WI * 4);
    if (off > ws_size) return;  // core workspace too small — fail visibly
    // bf16 copy of vis (98 MB); fallback to fp32-A path if no room
    ushort* vis_bf = nullptr;
    {
        const size_t need = (size_t)BB * NR * DV * 2;
        if (off + need <= ws_size) vis_bf = (ushort*)alloc(need);
    }

    // weight segment offsets (elements) within the pool
    const size_t O_ENC = 0;              // 256x1024
    const size_t O_HH  = 262144;         // 4096x1024 (row-interleaved)
    const size_t O_TH  = 4456448;        // 1024x1024
    const size_t O_SP  = 5505024;        // 256x1024
    const size_t O_SC  = 5767168;        // 256x1024
    const size_t O_DEC = 6029312;        // 256x1024 (hi used by att_step)
    const size_t O_IH2 = 6291456;        // 4096x1024 (plain, ws A)
    const size_t O_TC2 = 10485760;       // 1024x1024 (plain, ws A)

    CvtTab tab;
    const float* srcs[8] = {enc_att_w, W_hh, topic_hid_w, stop_prev_w, stop_cur_w,
                            dec_att_w, W_ih, topic_ctx_w};
    const size_t offs[8] = {O_ENC, O_HH, O_TH, O_SP, O_SC, O_DEC, O_IH2, O_TC2};
    for (int i = 0; i < 8; ++i) {
        tab.s[i] = srcs[i];
        tab.h[i] = wh + offs[i];
        tab.l[i] = wl + offs[i];
    }

    hipMemsetAsync(hh_h, 0, (size_t)BB * HH * 2, stream);    // h_0 hi = 0
    hipMemsetAsync(hh_l, 0, (size_t)BB * HH * 2, stream);    // h_0 lo = 0
    hipMemsetAsync(cbuf, 0, (size_t)BB * HH * 4, stream);    // c_0 = 0

    // ---- ONE merged setup dispatch: convert_split + transpose + foldbias
    //      + convert_vis (all independent; consumers follow) ----
    setup_all<<<38656, 256, 0, stream>>>(
        tab, ctx_w, ctT_h, ctT_l,
        W_ih, topic_ctx_w, ctx_b, b_ih, topic_ctx_b, bf_ih, bf_tc,
        vis, vis_bf);

    // ---- ctx-fold weight synthesis (both ws GEMMs in ONE dispatch) ----
    mgemm_wsp2<<<1280, 256, 0, stream>>>(
        wh + O_IH2, wl + O_IH2, cmb_h, cmb_l,
        wh + O_TC2, wl + O_TC2, tcc_h, tcc_l,
        ctT_h, ctT_l);

    // hoisted encoder projection
    mgemm_preb<<<(BB * NR) / 128, 512, 0, stream>>>(
        vis_bf, wh + O_ENC, wl + O_ENC, enc_att_b, vis_att);

    for (int s = 0; s < ST; ++s) {
        ushort* hch = hh_h + (size_t)s * BB * HH;
        ushort* hcl = hh_l + (size_t)s * BB * HH;
        ushort* hnh = hh_h + (size_t)(s + 1) * BB * HH;
        ushort* hnl = hh_l + (size_t)(s + 1) * BB * HH;
        ushort* ath = att_all_h + (size_t)s * BB * DV;
        ushort* atl = att_all_l + (size_t)s * BB * DV;
        // fused dec(bf16 w, h from hi+lo) + logits + softmax + apply
        att_step<1><<<BB, 1024, 0, stream>>>(vis_att, hch, hcl, wh + O_DEC, dec_att_b,
                                             full_att_w, full_att_b, vis_bf,
                                             ath, atl);
        // gates = att @ W_comb^T + bf_ih + h @ W_hh^T + b_hh, fused LSTM
        mgemm8_lstm<<<dim3(4 * HH / 32, BB / 64), 512, 0, stream>>>(
            ath, atl, cmb_h, cmb_l, bf_ih,
            hch, hcl, wh + O_HH, wl + O_HH, b_hh,
            SI, cbuf, hnh, hnl);
    }

    // deferred heads: topic (640 blocks) + stop (160 blocks) in ONE dispatch
    mgemm_heads<<<800, 256, 0, stream>>>(
        hh_h + (size_t)BB * HH, hh_l + (size_t)BB * HH,
        wh + O_TH, wl + O_TH, topic_hid_b,
        att_all_h, att_all_l, tcc_h, tcc_l, bf_tc,
        out_topics,
        hh_h, hh_l, wh + O_SP, wl + O_SP, stop_prev_b,
        hh_h + (size_t)BB * HH, hh_l + (size_t)BB * HH,
        wh + O_SC, wl + O_SC, stop_cur_b,
        pt_all);
    stop_final_all<<<ST * BB, 256, 0, stream>>>(pt_all, final_stop_w, final_stop_b, out_ps);
}